// Round 4
// baseline (852.156 us; speedup 1.0000x reference)
//
#include <hip/hip_runtime.h>
#include <math.h>

typedef unsigned short u16;
typedef __bf16 bf16x8 __attribute__((ext_vector_type(8)));
typedef float f32x4 __attribute__((ext_vector_type(4)));

#define T_TOK 4096
#define DIMD 2048
#define HIDD 1024
#define NEXP 16
#define RMAX 10240
#define MAXBLK 96
#define BM 128
#define BN 256
#define BK 64

__device__ __forceinline__ u16 f2b(float f) {
  unsigned u = __builtin_bit_cast(unsigned, f);
  unsigned r = (u + 0x7FFFu + ((u >> 16) & 1u)) >> 16;  // RNE
  return (u16)r;
}

__device__ __forceinline__ void gld16(const void* g, void* l) {
  __builtin_amdgcn_global_load_lds(
      (const __attribute__((address_space(1))) void*)g,
      (__attribute__((address_space(3))) void*)l, 16, 0, 0);
}

// ---------------- small kernels ----------------

__global__ void k_zero(float* __restrict__ o) {
  const int i = blockIdx.x * blockDim.x + threadIdx.x;
  float4 z = {0.f, 0.f, 0.f, 0.f};
  ((float4*)o)[i] = z;
}

__global__ void k_init(int* perm, int* cnt, int* fill) {
  int i = blockIdx.x * blockDim.x + threadIdx.x;
  if (i < RMAX) perm[i] = -1;
  if (i < NEXP) { cnt[i] = 0; fill[i] = 0; }
}

__global__ void k_cvt(const float* __restrict__ x, u16* __restrict__ xb) {
  const int i = blockIdx.x * blockDim.x + threadIdx.x;
  const float4 v = ((const float4*)x)[i];
  union { u16 u[4]; unsigned long long q; } t;
  t.u[0] = f2b(v.x); t.u[1] = f2b(v.y); t.u[2] = f2b(v.z); t.u[3] = f2b(v.w);
  ((unsigned long long*)xb)[i] = t.q;
}

// transpose+convert: W fp32 [E][K][N] -> Wt bf16 rows of n: Wt[e-part][n][k]
__global__ __launch_bounds__(256)
void k_tr(const float* __restrict__ W, u16* __restrict__ Wt,
          int K, int N, long estride, int ld_out) {
  __shared__ float t[64][65];
  const int e = blockIdx.z;
  const float* Win = W + (size_t)e * (size_t)K * (size_t)N;
  u16* Wo = Wt + (size_t)e * (size_t)estride;
  const int n0 = blockIdx.x * 64, k0 = blockIdx.y * 64;
  const int r = threadIdx.x >> 4;
  const int c = (threadIdx.x & 15) * 4;
#pragma unroll
  for (int p = 0; p < 4; ++p) {
    const int kk = p * 16 + r;
    const float4 v = *(const float4*)&Win[(size_t)(k0 + kk) * N + n0 + c];
    t[kk][c] = v.x; t[kk][c + 1] = v.y; t[kk][c + 2] = v.z; t[kk][c + 3] = v.w;
  }
  __syncthreads();
#pragma unroll
  for (int p = 0; p < 4; ++p) {
    const int nn = p * 16 + r;
    ushort4 o;
    o.x = f2b(t[c + 0][nn]); o.y = f2b(t[c + 1][nn]);
    o.z = f2b(t[c + 2][nn]); o.w = f2b(t[c + 3][nn]);
    *(ushort4*)&Wo[(size_t)(n0 + nn) * ld_out + k0 + c] = o;
  }
}

// gating: fp32 logits = x @ gate_w, softmax, top-2, partial prob sums
__global__ __launch_bounds__(256)
void k_gate(const float* __restrict__ x, const float* __restrict__ gw,
            int* __restrict__ top2i, float* __restrict__ top2w,
            int* __restrict__ cnt, float* __restrict__ partial) {
  const int e = threadIdx.x & 15;
  const int tt = threadIdx.x >> 4;
  const int t = blockIdx.x * 16 + tt;
  const float* xp = x + (size_t)t * DIMD;
  float acc = 0.f;
#pragma unroll 8
  for (int k = 0; k < DIMD; ++k) acc = fmaf(xp[k], gw[k * NEXP + e], acc);
  __shared__ float lg[16][17];
  __shared__ float pr[16][17];
  lg[tt][e] = acc;
  __syncthreads();
  if (e == 0) {
    float l[16];
    float mx = -1e30f;
    for (int j = 0; j < 16; ++j) { l[j] = lg[tt][j]; mx = fmaxf(mx, l[j]); }
    float s = 0.f;
    for (int j = 0; j < 16; ++j) { l[j] = expf(l[j] - mx); s += l[j]; }
    const float inv = 1.f / s;
    float p1 = -1.f, p2 = -1.f; int i1 = 0, i2 = 0;
    for (int j = 0; j < 16; ++j) {
      const float p = l[j] * inv;
      pr[tt][j] = p;
      if (p > p1) { p2 = p1; i2 = i1; p1 = p; i1 = j; }
      else if (p > p2) { p2 = p; i2 = j; }
    }
    const float wsum = p1 + p2;
    top2i[t * 2 + 0] = i1;
    top2i[t * 2 + 1] = i2;
    top2w[t * 2 + 0] = p1 / wsum;
    top2w[t * 2 + 1] = p2 / wsum;
    atomicAdd(&cnt[i1], 1);
    atomicAdd(&cnt[i2], 1);
  }
  __syncthreads();
  if (tt == 0) {
    float s = 0.f;
    for (int j = 0; j < 16; ++j) s += pr[j][e];
    partial[blockIdx.x * 16 + e] = s;
  }
}

__global__ __launch_bounds__(256)
void k_aux(const float* __restrict__ partial, float* __restrict__ auxOut) {
  __shared__ float s[16][17];
  const int e = threadIdx.x & 15, c = threadIdx.x >> 4;
  float a = 0.f;
  for (int b = c; b < 256; b += 16) a += partial[b * 16 + e];
  s[c][e] = a;
  __syncthreads();
  if (threadIdx.x == 0) {
    float aux = 0.f;
    for (int j = 0; j < 16; ++j) {
      float tot = 0.f;
      for (int cc = 0; cc < 16; ++cc) tot += s[cc][j];
      const float m = tot / (float)T_TOK;
      aux += m * m;
    }
    auxOut[0] = aux * (float)NEXP;
  }
}

__global__ void k_off(const int* __restrict__ cnt, int* __restrict__ offs,
                      int* __restrict__ tbl_e, int* __restrict__ tbl_r0,
                      int* __restrict__ nblk) {
  if (threadIdx.x != 0 || blockIdx.x != 0) return;
  int o = 0, nb = 0;
  for (int e = 0; e < NEXP; ++e) {
    offs[e] = o;
    const int b = (cnt[e] + BM - 1) / BM;
    for (int i = 0; i < b; ++i) { tbl_e[nb] = e; tbl_r0[nb] = o + i * BM; ++nb; }
    o += b * BM;
  }
  offs[NEXP] = o;
  nblk[0] = nb;
}

__global__ void k_fill(const int* __restrict__ top2i, const float* __restrict__ top2w,
                       const int* __restrict__ offs, int* __restrict__ fill,
                       int* __restrict__ perm, float* __restrict__ wrow) {
  const int id = blockIdx.x * blockDim.x + threadIdx.x;
  if (id >= T_TOK * 2) return;
  const int e = top2i[id];
  const int pos = atomicAdd(&fill[e], 1);
  const int r = offs[e] + pos;
  perm[r] = id >> 1;
  wrow[r] = top2w[id];
}

// ---------------- GEMM core: counted-vmcnt RING-3 pipeline ----------------
// Tile BM=128 x BN=256, BK=64. 512 threads = 8 waves (2M x 4N), 64x64 C/wave.
// LDS: 3 buffers x (A 16KB + B 32KB) = 144 KB. Two tiles always in flight:
// per K-tile: compute(buf t%3) ; bar ; stage(t+3 -> same buf) ; vmcnt(12)
// (= tile t+1 landed, 12 newer in flight) ; bar.  The vmcnt is per-wave; the
// following barrier certifies ALL waves' loads for t+1 have landed.
// Swizzle (kept, conflicts measured 0): LDS slot (row, chunk c) holds global
// chunk c ^ ((row>>1)&7); applied on per-lane GLOBAL source + ds_read addr.

__device__ __forceinline__ void stage_tile(
    const u16* gA0, const u16* gA1, const u16* gB0, const u16* gB1,
    const u16* gB2, const u16* gB3, int k0, u16* S, int b, int w) {
  u16* As = S + b * 24576;
  u16* Bs = As + 8192;
  gld16(gA0 + k0, As + w * 512);
  gld16(gA1 + k0, As + 4096 + w * 512);
  gld16(gB0 + k0, Bs + w * 512);
  gld16(gB1 + k0, Bs + 4096 + w * 512);
  gld16(gB2 + k0, Bs + 8192 + w * 512);
  gld16(gB3 + k0, Bs + 12288 + w * 512);
}

__device__ __forceinline__ void comp_tile(const u16* __restrict__ S, int b,
    const int (&aoff)[4][2], const int (&boff)[4][2], f32x4 (&acc)[4][4]) {
  const u16* As = S + b * 24576;
  const u16* Bs = As + 8192;
#pragma unroll
  for (int kh = 0; kh < 2; ++kh) {
    bf16x8 a[4], bq[4];
#pragma unroll
    for (int i = 0; i < 4; ++i) a[i] = *(const bf16x8*)(As + aoff[i][kh]);
#pragma unroll
    for (int j = 0; j < 4; ++j) bq[j] = *(const bf16x8*)(Bs + boff[j][kh]);
    __builtin_amdgcn_s_setprio(1);
#pragma unroll
    for (int i = 0; i < 4; ++i)
#pragma unroll
      for (int j = 0; j < 4; ++j)
        acc[i][j] = __builtin_amdgcn_mfma_f32_16x16x32_bf16(a[i], bq[j], acc[i][j], 0, 0, 0);
    __builtin_amdgcn_s_setprio(0);
  }
}

#define FENCE asm volatile("" ::: "memory")
#define VMW12 asm volatile("s_waitcnt vmcnt(12)" ::: "memory")
#define VMW6  asm volatile("s_waitcnt vmcnt(6)" ::: "memory")
#define VMW0  asm volatile("s_waitcnt vmcnt(0)" ::: "memory")

__device__ __forceinline__ void gemm_pipe(
    const u16* gA0, const u16* gA1, const u16* gB0, const u16* gB1,
    const u16* gB2, const u16* gB3, int K, u16* S,
    const int (&aoff)[4][2], const int (&boff)[4][2],
    f32x4 (&acc)[4][4], int w) {
  const int nt = K >> 6;  // 16 or 32 (always >= 4)
  stage_tile(gA0, gA1, gB0, gB1, gB2, gB3, 0, S, 0, w);
  stage_tile(gA0, gA1, gB0, gB1, gB2, gB3, 64, S, 1, w);
  stage_tile(gA0, gA1, gB0, gB1, gB2, gB3, 128, S, 2, w);
  VMW12;                             // tile0 landed; t1,t2 in flight
  __builtin_amdgcn_s_barrier();
  FENCE;
  int b = 0;
  for (int t = 0; t < nt - 3; ++t) {
    comp_tile(S, b, aoff, boff, acc);
    FENCE;
    __builtin_amdgcn_s_barrier();    // all waves done reading buf b
    FENCE;
    stage_tile(gA0, gA1, gB0, gB1, gB2, gB3, (t + 3) << 6, S, b, w);
    VMW12;                           // tile t+1 landed (own); t+2,t+3 flying
    __builtin_amdgcn_s_barrier();    // now ALL waves' t+1 loads landed
    FENCE;
    b = (b == 2) ? 0 : b + 1;
  }
  // tail: tiles nt-3, nt-2, nt-1 in buffers b, b+1, b+2 (mod 3)
  comp_tile(S, b, aoff, boff, acc);
  FENCE;
  VMW6;                              // own nt-2 landed
  __builtin_amdgcn_s_barrier();      // all waves' nt-2 landed
  FENCE;
  b = (b == 2) ? 0 : b + 1;
  comp_tile(S, b, aoff, boff, acc);
  FENCE;
  VMW0;                              // own nt-1 landed
  __builtin_amdgcn_s_barrier();      // all waves' nt-1 landed
  FENCE;
  b = (b == 2) ? 0 : b + 1;
  comp_tile(S, b, aoff, boff, acc);
}

// Fused up-projection. grid(8, 32+MAXBLK); gridDim.x=8 so linear workgroup
// id % 8 == blockIdx.x -> each n-tile pinned to one XCD (B-panel L2 reuse).
// y<32: shared, n0=x*256 over concat-N 2048, r0=y*128, K=2048.
// y>=32: routed rbx=y-32 (expert-ordered), n-tile=(x>>1) over N=1024,
//        parity split: handled iff (rbx&1)==(x&1). K=2048.
__global__ __launch_bounds__(512, 2)
void k_up(const u16* __restrict__ xb, const u16* __restrict__ sw1t,
          const u16* __restrict__ w1t, u16* __restrict__ hbS,
          u16* __restrict__ hbR, const int* __restrict__ perm,
          const int* __restrict__ tbl_e, const int* __restrict__ tbl_r0,
          const int* __restrict__ nblk) {
  __shared__ u16 S[73728];  // 144 KB
  const int bx = blockIdx.x, by = blockIdx.y;
  const int tid = threadIdx.x;
  const int w = tid >> 6, lane = tid & 63;
  const int lm = lane & 15, lq = lane >> 4;
  const int wm = w >> 2, wn = w & 3;
  const int srow = w * 8 + (lane >> 3);  // 0..63 staging row
  const int c8 = lane & 7;               // 16B chunk within 64-elem row

  const bool routed = by >= 32;
  int r0, n0, ga0, ga1;
  const u16* Bb;
  if (!routed) {
    r0 = by * BM;
    n0 = bx * BN;
    Bb = sw1t;  // concat-n [2048][2048]
    ga0 = r0 + srow; ga1 = r0 + 64 + srow;
  } else {
    const int rbx = by - 32;
    if (rbx >= *nblk) return;
    if ((rbx & 1) != (bx & 1)) return;   // parity split across XCD pairs
    n0 = (bx >> 1) * BN;                 // 4 n-tiles of 256 (N=1024)
    const int e = tbl_e[rbx];
    r0 = tbl_r0[rbx];
    Bb = w1t + (size_t)e * (size_t)HIDD * DIMD;
    const int p0 = perm[r0 + srow];      ga0 = (p0 < 0) ? 0 : p0;
    const int p1 = perm[r0 + 64 + srow]; ga1 = (p1 < 0) ? 0 : p1;
  }
  // pre-swizzled global sources (linear LDS dest => swizzle on source)
  const u16* gA0 = xb + (size_t)ga0 * DIMD + (c8 ^ ((srow >> 1) & 7)) * 8;
  const u16* gA1 = xb + (size_t)ga1 * DIMD + (c8 ^ (((64 + srow) >> 1) & 7)) * 8;
  const u16* gB[4];
#pragma unroll
  for (int p = 0; p < 4; ++p) {
    const int n = p * 64 + srow;
    gB[p] = Bb + (size_t)(n0 + n) * DIMD + (c8 ^ ((n >> 1) & 7)) * 8;
  }
  int aoff[4][2], boff[4][2];
#pragma unroll
  for (int i = 0; i < 4; ++i) {
    const int m = wm * 64 + i * 16 + lm;
    const int n = wn * 64 + i * 16 + lm;
#pragma unroll
    for (int kh = 0; kh < 2; ++kh) {
      aoff[i][kh] = m * 64 + (((kh << 2) | lq) ^ ((m >> 1) & 7)) * 8;
      boff[i][kh] = n * 64 + (((kh << 2) | lq) ^ ((n >> 1) & 7)) * 8;
    }
  }
  f32x4 acc[4][4];
#pragma unroll
  for (int i = 0; i < 4; ++i)
#pragma unroll
    for (int j = 0; j < 4; ++j) {
      acc[i][j][0] = 0.f; acc[i][j][1] = 0.f; acc[i][j][2] = 0.f; acc[i][j][3] = 0.f;
    }

  gemm_pipe(gA0, gA1, gB[0], gB[1], gB[2], gB[3], DIMD, S, aoff, boff, acc, w);

#pragma unroll
  for (int i = 0; i < 4; ++i) {
#pragma unroll
    for (int r = 0; r < 4; ++r) {
      const int row = r0 + wm * 64 + i * 16 + lq * 4 + r;
      u16* dst = routed ? &hbR[(size_t)row * HIDD] : &hbS[(size_t)row * DIMD];
#pragma unroll
      for (int j = 0; j < 4; ++j) {
        const int gc = n0 + wn * 64 + j * 16 + lm;
        const float v = acc[i][j][r];
        const float s = v / (1.f + expf(-v));
        dst[gc] = f2b(s);
      }
    }
  }
}

// Fused down-projection. grid(8, 32+MAXBLK); x = n-tile (N=2048 both paths,
// XCD-pinned). y<32: shared A=hbS K=2048 B=sw2ct. y>=32: routed rbx=y-32,
// A=hbR K=1024, B=w2t[e]. out pre-zeroed; atomicAdd accumulation.
__global__ __launch_bounds__(512, 2)
void k_down(const u16* __restrict__ hbS, const u16* __restrict__ hbR,
            const u16* __restrict__ sw2ct, const u16* __restrict__ w2t,
            float* __restrict__ out, const int* __restrict__ perm,
            const float* __restrict__ wrow,
            const int* __restrict__ tbl_e, const int* __restrict__ tbl_r0,
            const int* __restrict__ nblk) {
  __shared__ u16 S[73728];
  const int bx = blockIdx.x, by = blockIdx.y;
  const int tid = threadIdx.x;
  const int w = tid >> 6, lane = tid & 63;
  const int lm = lane & 15, lq = lane >> 4;
  const int wm = w >> 2, wn = w & 3;
  const int srow = w * 8 + (lane >> 3);
  const int c8 = lane & 7;

  const bool routed = by >= 32;
  int r0, K, ld;
  const u16 *Ab, *Bb;
  if (!routed) {
    r0 = by * BM;
    Ab = hbS; K = DIMD; ld = DIMD;
    Bb = sw2ct;
  } else {
    const int rbx = by - 32;
    if (rbx >= *nblk) return;
    const int e = tbl_e[rbx];
    r0 = tbl_r0[rbx];
    Ab = hbR; K = HIDD; ld = HIDD;
    Bb = w2t + (size_t)e * (size_t)DIMD * HIDD;
  }
  const int n0 = bx * BN;
  const u16* gA0 = Ab + (size_t)(r0 + srow) * ld + (c8 ^ ((srow >> 1) & 7)) * 8;
  const u16* gA1 = Ab + (size_t)(r0 + 64 + srow) * ld + (c8 ^ (((64 + srow) >> 1) & 7)) * 8;
  const u16* gB[4];
#pragma unroll
  for (int p = 0; p < 4; ++p) {
    const int n = p * 64 + srow;
    gB[p] = Bb + (size_t)(n0 + n) * ld + (c8 ^ ((n >> 1) & 7)) * 8;
  }
  int aoff[4][2], boff[4][2];
#pragma unroll
  for (int i = 0; i < 4; ++i) {
    const int m = wm * 64 + i * 16 + lm;
    const int n = wn * 64 + i * 16 + lm;
#pragma unroll
    for (int kh = 0; kh < 2; ++kh) {
      aoff[i][kh] = m * 64 + (((kh << 2) | lq) ^ ((m >> 1) & 7)) * 8;
      boff[i][kh] = n * 64 + (((kh << 2) | lq) ^ ((n >> 1) & 7)) * 8;
    }
  }
  f32x4 acc[4][4];
#pragma unroll
  for (int i = 0; i < 4; ++i)
#pragma unroll
    for (int j = 0; j < 4; ++j) {
      acc[i][j][0] = 0.f; acc[i][j][1] = 0.f; acc[i][j][2] = 0.f; acc[i][j][3] = 0.f;
    }

  gemm_pipe(gA0, gA1, gB[0], gB[1], gB[2], gB[3], K, S, aoff, boff, acc, w);

#pragma unroll
  for (int i = 0; i < 4; ++i) {
#pragma unroll
    for (int r = 0; r < 4; ++r) {
      const int rr = r0 + wm * 64 + i * 16 + lq * 4 + r;
      int t; float wt;
      if (!routed) { t = rr; wt = 1.f; }
      else { t = perm[rr]; wt = (t >= 0) ? wrow[rr] : 0.f; }
      if (t >= 0) {
        float* dst = &out[(size_t)t * DIMD];
#pragma unroll
        for (int j = 0; j < 4; ++j) {
          const int gc = n0 + wn * 64 + j * 16 + lm;
          atomicAdd(&dst[gc], wt * acc[i][j][r]);
        }
      }
    }
  }
}

// ---------------- launch ----------------

extern "C" void kernel_launch(void* const* d_in, const int* in_sizes, int n_in,
                              void* d_out, int out_size, void* d_ws, size_t ws_size,
                              hipStream_t stream) {
  const float* x   = (const float*)d_in[0];
  const float* gw  = (const float*)d_in[1];
  const float* sw1 = (const float*)d_in[2];
  const float* sw2 = (const float*)d_in[3];
  const float* w1  = (const float*)d_in[4];
  const float* w2  = (const float*)d_in[5];
  float* out = (float*)d_out;

  char* ws = (char*)d_ws;
  u16* xb    = (u16*)(ws);                         // 16 MB
  u16* hbS   = (u16*)(ws + (size_t)( 16 << 20));   // 16 MB  [4096][2048]
  u16* hbR   = (u16*)(ws + (size_t)( 32 << 20));   // 20 MB  [10240][1024]
  u16* sw1t  = (u16*)(ws + (size_t)( 56 << 20));   //  8 MB  [2][1024][2048] (concat n)
  u16* sw2ct = (u16*)(ws + (size_t)( 64 << 20));   //  8 MB  [2048][2*1024] concat k
  u16* w1t   = (u16*)(ws + (size_t)( 72 << 20));   // 64 MB  [16][1024][2048]
  u16* w2t   = (u16*)(ws + (size_t)(136 << 20));   // 64 MB  [16][2048][1024]
  char* p = ws + (size_t)(200 << 20);
  int*   top2i   = (int*)p;    p += T_TOK * 2 * 4;
  float* top2w   = (float*)p;  p += T_TOK * 2 * 4;
  int*   perm    = (int*)p;    p += RMAX * 4;
  float* wrow    = (float*)p;  p += RMAX * 4;
  int*   cnt     = (int*)p;    p += 16 * 4;
  int*   fill    = (int*)p;    p += 16 * 4;
  int*   offs    = (int*)p;    p += 32 * 4;
  int*   tbl_e   = (int*)p;    p += MAXBLK * 4;
  int*   tbl_r0  = (int*)p;    p += MAXBLK * 4;
  int*   nblk    = (int*)p;    p += 16 * 4;
  float* partial = (float*)p;  p += 256 * 16 * 4;

  // out must be zero before k_down's atomic accumulation
  k_zero<<<(T_TOK * DIMD / 4) / 256, 256, 0, stream>>>(out);
  k_init<<<(RMAX + 255) / 256, 256, 0, stream>>>(perm, cnt, fill);
  k_cvt<<<(T_TOK * DIMD / 4) / 256, 256, 0, stream>>>(x, xb);
  k_gate<<<T_TOK / 16, 256, 0, stream>>>(x, gw, top2i, top2w, cnt, partial);
  k_off<<<1, 64, 0, stream>>>(cnt, offs, tbl_e, tbl_r0, nblk);
  k_fill<<<(T_TOK * 2 + 255) / 256, 256, 0, stream>>>(top2i, top2w, offs, fill, perm, wrow);
  k_aux<<<1, 256, 0, stream>>>(partial, out + (size_t)T_TOK * DIMD);

  // weight transposes (fp32 [K][N] -> bf16 [n][k])
  k_tr<<<dim3(1024 / 64, 2048 / 64,  2), 256, 0, stream>>>(sw1, sw1t, 2048, 1024, 1024l * 2048, 2048);
  k_tr<<<dim3(2048 / 64, 1024 / 64,  2), 256, 0, stream>>>(sw2, sw2ct, 1024, 2048, 1024, 2048);
  k_tr<<<dim3(1024 / 64, 2048 / 64, 16), 256, 0, stream>>>(w1, w1t, 2048, 1024, 1024l * 2048, 2048);
  k_tr<<<dim3(2048 / 64, 1024 / 64, 16), 256, 0, stream>>>(w2, w2t, 1024, 2048, 2048l * 1024, 1024);

  // fused up-projection: x = n-tile (XCD-pinned), y = row-block
  k_up<<<dim3(8, 32 + MAXBLK), 512, 0, stream>>>(xb, sw1t, w1t, hbS, hbR,
                                                 perm, tbl_e, tbl_r0, nblk);
  // fused down-projection: x = n-tile (XCD-pinned), y = row-block
  k_down<<<dim3(8, 32 + MAXBLK), 512, 0, stream>>>(hbS, hbR, sw2ct, w2t, out,
                                                   perm, wrow, tbl_e, tbl_r0, nblk);
}

// Round 5
// 806.505 us; speedup vs baseline: 1.0566x; 1.0566x over previous
//
#include <hip/hip_runtime.h>
#include <math.h>

typedef unsigned short u16;
typedef __bf16 bf16x8 __attribute__((ext_vector_type(8)));
typedef float f32x4 __attribute__((ext_vector_type(4)));
typedef unsigned short u16x8 __attribute__((ext_vector_type(8)));

#define T_TOK 4096
#define DIMD 2048
#define HIDD 1024
#define NEXP 16
#define RMAX 10240
#define MAXBLK 96
#define BM 128
#define BN 256
#define BK 64

__device__ __forceinline__ u16 f2b(float f) {
  unsigned u = __builtin_bit_cast(unsigned, f);
  unsigned r = (u + 0x7FFFu + ((u >> 16) & 1u)) >> 16;  // RNE
  return (u16)r;
}

__device__ __forceinline__ void gld16(const void* g, void* l) {
  __builtin_amdgcn_global_load_lds(
      (const __attribute__((address_space(1))) void*)g,
      (__attribute__((address_space(3))) void*)l, 16, 0, 0);
}

// ---------------- small kernels ----------------

// fused: zero(out) + cvt(x->xb bf16) + init(perm/cnt/fill)
__global__ void k_pre(const float* __restrict__ x, u16* __restrict__ xb,
                      float* __restrict__ out, int* __restrict__ perm,
                      int* __restrict__ cnt, int* __restrict__ fill) {
  const int i = blockIdx.x * blockDim.x + threadIdx.x;  // 0 .. T*D/4-1
  const float4 v = ((const float4*)x)[i];
  union { u16 u[4]; unsigned long long q; } t;
  t.u[0] = f2b(v.x); t.u[1] = f2b(v.y); t.u[2] = f2b(v.z); t.u[3] = f2b(v.w);
  ((unsigned long long*)xb)[i] = t.q;
  float4 z = {0.f, 0.f, 0.f, 0.f};
  ((float4*)out)[i] = z;
  if (i < RMAX) perm[i] = -1;
  if (i < NEXP) { cnt[i] = 0; fill[i] = 0; }
}

// transpose+convert v2: W fp32 [E][K][N] -> Wt bf16 [e][n][k].
// Distinct symbol per tensor (template ID) so rocprof names each dispatch.
// Load: 4 passes x 16 k-rows (float4/lane). Store: 2 passes x 32 n-rows,
// one 16B ushort8 per thread (banks: (8g+i+r2)%32 -> 2-way, free).
template <int ID>
__global__ __launch_bounds__(256)
void k_tr2(const float* __restrict__ W, u16* __restrict__ Wt,
           int K, int N, long estride, int ld_out) {
  __shared__ float t[64][65];
  const int e = blockIdx.z;
  const float* Win = W + (size_t)e * (size_t)K * (size_t)N;
  u16* Wo = Wt + (size_t)e * (size_t)estride;
  const int n0 = blockIdx.x * 64, k0 = blockIdx.y * 64;
  {
    const int r = threadIdx.x >> 4;
    const int c = (threadIdx.x & 15) * 4;
#pragma unroll
    for (int p = 0; p < 4; ++p) {
      const int kk = p * 16 + r;
      const float4 v = *(const float4*)&Win[(size_t)(k0 + kk) * N + n0 + c];
      t[kk][c] = v.x; t[kk][c + 1] = v.y; t[kk][c + 2] = v.z; t[kk][c + 3] = v.w;
    }
  }
  __syncthreads();
  {
    const int r2 = threadIdx.x >> 3;        // 0..31 n-row
    const int g8 = (threadIdx.x & 7) * 8;   // k-group
#pragma unroll
    for (int p = 0; p < 2; ++p) {
      const int nn = p * 32 + r2;
      u16x8 o;
#pragma unroll
      for (int i = 0; i < 8; ++i) o[i] = f2b(t[g8 + i][nn]);
      *(u16x8*)&Wo[(size_t)(n0 + nn) * ld_out + k0 + g8] = o;
    }
  }
}

// gating: fp32 logits = x @ gate_w, softmax, top-2, partial prob sums
__global__ __launch_bounds__(256)
void k_gate(const float* __restrict__ x, const float* __restrict__ gw,
            int* __restrict__ top2i, float* __restrict__ top2w,
            int* __restrict__ cnt, float* __restrict__ partial) {
  const int e = threadIdx.x & 15;
  const int tt = threadIdx.x >> 4;
  const int t = blockIdx.x * 16 + tt;
  const float* xp = x + (size_t)t * DIMD;
  float acc = 0.f;
#pragma unroll 8
  for (int k = 0; k < DIMD; ++k) acc = fmaf(xp[k], gw[k * NEXP + e], acc);
  __shared__ float lg[16][17];
  __shared__ float pr[16][17];
  lg[tt][e] = acc;
  __syncthreads();
  if (e == 0) {
    float l[16];
    float mx = -1e30f;
    for (int j = 0; j < 16; ++j) { l[j] = lg[tt][j]; mx = fmaxf(mx, l[j]); }
    float s = 0.f;
    for (int j = 0; j < 16; ++j) { l[j] = expf(l[j] - mx); s += l[j]; }
    const float inv = 1.f / s;
    float p1 = -1.f, p2 = -1.f; int i1 = 0, i2 = 0;
    for (int j = 0; j < 16; ++j) {
      const float p = l[j] * inv;
      pr[tt][j] = p;
      if (p > p1) { p2 = p1; i2 = i1; p1 = p; i1 = j; }
      else if (p > p2) { p2 = p; i2 = j; }
    }
    const float wsum = p1 + p2;
    top2i[t * 2 + 0] = i1;
    top2i[t * 2 + 1] = i2;
    top2w[t * 2 + 0] = p1 / wsum;
    top2w[t * 2 + 1] = p2 / wsum;
    atomicAdd(&cnt[i1], 1);
    atomicAdd(&cnt[i2], 1);
  }
  __syncthreads();
  if (tt == 0) {
    float s = 0.f;
    for (int j = 0; j < 16; ++j) s += pr[j][e];
    partial[blockIdx.x * 16 + e] = s;
  }
}

__global__ __launch_bounds__(256)
void k_aux(const float* __restrict__ partial, float* __restrict__ auxOut) {
  __shared__ float s[16][17];
  const int e = threadIdx.x & 15, c = threadIdx.x >> 4;
  float a = 0.f;
  for (int b = c; b < 256; b += 16) a += partial[b * 16 + e];
  s[c][e] = a;
  __syncthreads();
  if (threadIdx.x == 0) {
    float aux = 0.f;
    for (int j = 0; j < 16; ++j) {
      float tot = 0.f;
      for (int cc = 0; cc < 16; ++cc) tot += s[cc][j];
      const float m = tot / (float)T_TOK;
      aux += m * m;
    }
    auxOut[0] = aux * (float)NEXP;
  }
}

__global__ void k_off(const int* __restrict__ cnt, int* __restrict__ offs,
                      int* __restrict__ tbl_e, int* __restrict__ tbl_r0,
                      int* __restrict__ nblk) {
  if (threadIdx.x != 0 || blockIdx.x != 0) return;
  int o = 0, nb = 0;
  for (int e = 0; e < NEXP; ++e) {
    offs[e] = o;
    const int b = (cnt[e] + BM - 1) / BM;
    for (int i = 0; i < b; ++i) { tbl_e[nb] = e; tbl_r0[nb] = o + i * BM; ++nb; }
    o += b * BM;
  }
  offs[NEXP] = o;
  nblk[0] = nb;
}

__global__ void k_fill(const int* __restrict__ top2i, const float* __restrict__ top2w,
                       const int* __restrict__ offs, int* __restrict__ fill,
                       int* __restrict__ perm, float* __restrict__ wrow) {
  const int id = blockIdx.x * blockDim.x + threadIdx.x;
  if (id >= T_TOK * 2) return;
  const int e = top2i[id];
  const int pos = atomicAdd(&fill[e], 1);
  const int r = offs[e] + pos;
  perm[r] = id >> 1;
  wrow[r] = top2w[id];
}

// ---------------- GEMM core: counted-vmcnt ring-2 pipeline (R3, best) ------
// Tile BM=128 x BN=256, BK=64. 512 threads = 8 waves (2M x 4N), 64x64 C/wave.
// LDS per buffer: A 16KB + B 32KB; ring of 2 = 96KB.
// Swizzle (conflicts measured 0): LDS slot (row, chunk c) holds global chunk
// c ^ ((row>>1)&7); applied on per-lane GLOBAL source + ds_read address.
// Per K-tile: compute(buf) ; bar ; stage(t+2 -> buf) ; vmcnt(6) ; bar.

__device__ __forceinline__ void stage_tile(
    const u16* gA0, const u16* gA1, const u16* gB0, const u16* gB1,
    const u16* gB2, const u16* gB3, int k0, u16* S, int b, int w) {
  u16* As = S + b * 24576;
  u16* Bs = As + 8192;
  gld16(gA0 + k0, As + w * 512);
  gld16(gA1 + k0, As + 4096 + w * 512);
  gld16(gB0 + k0, Bs + w * 512);
  gld16(gB1 + k0, Bs + 4096 + w * 512);
  gld16(gB2 + k0, Bs + 8192 + w * 512);
  gld16(gB3 + k0, Bs + 12288 + w * 512);
}

__device__ __forceinline__ void comp_tile(const u16* __restrict__ S, int b,
    const int (&aoff)[4][2], const int (&boff)[4][2], f32x4 (&acc)[4][4]) {
  const u16* As = S + b * 24576;
  const u16* Bs = As + 8192;
#pragma unroll
  for (int kh = 0; kh < 2; ++kh) {
    bf16x8 a[4], bq[4];
#pragma unroll
    for (int i = 0; i < 4; ++i) a[i] = *(const bf16x8*)(As + aoff[i][kh]);
#pragma unroll
    for (int j = 0; j < 4; ++j) bq[j] = *(const bf16x8*)(Bs + boff[j][kh]);
    __builtin_amdgcn_s_setprio(1);
#pragma unroll
    for (int i = 0; i < 4; ++i)
#pragma unroll
      for (int j = 0; j < 4; ++j)
        acc[i][j] = __builtin_amdgcn_mfma_f32_16x16x32_bf16(a[i], bq[j], acc[i][j], 0, 0, 0);
    __builtin_amdgcn_s_setprio(0);
  }
}

#define FENCE asm volatile("" ::: "memory")
#define VMW6  asm volatile("s_waitcnt vmcnt(6)" ::: "memory")
#define VMW0  asm volatile("s_waitcnt vmcnt(0)" ::: "memory")

__device__ __forceinline__ void gemm_pipe(
    const u16* gA0, const u16* gA1, const u16* gB0, const u16* gB1,
    const u16* gB2, const u16* gB3, int K, u16* S,
    const int (&aoff)[4][2], const int (&boff)[4][2],
    f32x4 (&acc)[4][4], int w) {
  const int nt = K >> 6;  // even (16 or 32)
  stage_tile(gA0, gA1, gB0, gB1, gB2, gB3, 0, S, 0, w);
  stage_tile(gA0, gA1, gB0, gB1, gB2, gB3, 64, S, 1, w);
  VMW6;                              // tile0 landed (tile1's 6 in flight)
  __builtin_amdgcn_s_barrier();
  FENCE;
  for (int t = 0; t < nt - 2; ++t) {
    comp_tile(S, t & 1, aoff, boff, acc);
    FENCE;
    __builtin_amdgcn_s_barrier();    // all waves done reading buf (t&1)
    FENCE;
    stage_tile(gA0, gA1, gB0, gB1, gB2, gB3, (t + 2) << 6, S, t & 1, w);
    VMW6;                            // tile t+1 landed; t+2's 6 in flight
    __builtin_amdgcn_s_barrier();
    FENCE;
  }
  comp_tile(S, 0, aoff, boff, acc);  // tile nt-2
  VMW0;                              // tile nt-1 landed
  __builtin_amdgcn_s_barrier();
  FENCE;
  comp_tile(S, 1, aoff, boff, acc);  // tile nt-1
}

// Fused up-projection. Shared (bx<32): concat-N B = sw1t [2048n][2048k],
// out hbS [4096][2048]. Routed (bx>=32, by<4): per-expert B, out hbR.
// K=2048, lda=ldb=2048 for all.
__global__ __launch_bounds__(512, 2)
void k_up(const u16* __restrict__ xb, const u16* __restrict__ sw1t,
          const u16* __restrict__ w1t, u16* __restrict__ hbS,
          u16* __restrict__ hbR, const int* __restrict__ perm,
          const int* __restrict__ tbl_e, const int* __restrict__ tbl_r0,
          const int* __restrict__ nblk) {
  __shared__ u16 S[49152];  // 96 KB
  const int bx = blockIdx.x, by = blockIdx.y;
  const int tid = threadIdx.x;
  const int w = tid >> 6, lane = tid & 63;
  const int lm = lane & 15, lq = lane >> 4;
  const int wm = w >> 2, wn = w & 3;
  const int srow = w * 8 + (lane >> 3);  // 0..63 staging row
  const int c8 = lane & 7;               // 16B chunk within 64-elem row

  const bool routed = bx >= 32;
  int r0, ga0, ga1;
  const u16* Bb;
  if (!routed) {
    r0 = bx * BM;
    Bb = sw1t;  // concat-n [2048][2048]
    ga0 = r0 + srow; ga1 = r0 + 64 + srow;
  } else {
    if (by >= 4) return;
    const int rbx = bx - 32;
    if (rbx >= *nblk) return;
    const int e = tbl_e[rbx];
    r0 = tbl_r0[rbx];
    Bb = w1t + (size_t)e * (size_t)HIDD * DIMD;
    const int p0 = perm[r0 + srow];      ga0 = (p0 < 0) ? 0 : p0;
    const int p1 = perm[r0 + 64 + srow]; ga1 = (p1 < 0) ? 0 : p1;
  }
  const int n0 = by * BN;
  // pre-swizzled global sources (linear LDS dest => swizzle on source)
  const u16* gA0 = xb + (size_t)ga0 * DIMD + (c8 ^ ((srow >> 1) & 7)) * 8;
  const u16* gA1 = xb + (size_t)ga1 * DIMD + (c8 ^ (((64 + srow) >> 1) & 7)) * 8;
  const u16* gB[4];
#pragma unroll
  for (int p = 0; p < 4; ++p) {
    const int n = p * 64 + srow;
    gB[p] = Bb + (size_t)(n0 + n) * DIMD + (c8 ^ ((n >> 1) & 7)) * 8;
  }
  int aoff[4][2], boff[4][2];
#pragma unroll
  for (int i = 0; i < 4; ++i) {
    const int m = wm * 64 + i * 16 + lm;
    const int n = wn * 64 + i * 16 + lm;
#pragma unroll
    for (int kh = 0; kh < 2; ++kh) {
      aoff[i][kh] = m * 64 + (((kh << 2) | lq) ^ ((m >> 1) & 7)) * 8;
      boff[i][kh] = n * 64 + (((kh << 2) | lq) ^ ((n >> 1) & 7)) * 8;
    }
  }
  f32x4 acc[4][4];
#pragma unroll
  for (int i = 0; i < 4; ++i)
#pragma unroll
    for (int j = 0; j < 4; ++j) {
      acc[i][j][0] = 0.f; acc[i][j][1] = 0.f; acc[i][j][2] = 0.f; acc[i][j][3] = 0.f;
    }

  gemm_pipe(gA0, gA1, gB[0], gB[1], gB[2], gB[3], DIMD, S, aoff, boff, acc, w);

#pragma unroll
  for (int i = 0; i < 4; ++i) {
#pragma unroll
    for (int r = 0; r < 4; ++r) {
      const int row = r0 + wm * 64 + i * 16 + lq * 4 + r;
      u16* dst = routed ? &hbR[(size_t)row * HIDD] : &hbS[(size_t)row * DIMD];
#pragma unroll
      for (int j = 0; j < 4; ++j) {
        const int gc = n0 + wn * 64 + j * 16 + lm;
        const float v = acc[i][j][r];
        const float s = v / (1.f + expf(-v));
        dst[gc] = f2b(s);
      }
    }
  }
}

// Fused down-projection: shared (bx<32, A=hbS K=2048) + routed (bx>=32,
// A=hbR K=1024). N=2048 (by<8). out pre-zeroed; atomicAdd accumulation.
__global__ __launch_bounds__(512, 2)
void k_down(const u16* __restrict__ hbS, const u16* __restrict__ hbR,
            const u16* __restrict__ sw2ct, const u16* __restrict__ w2t,
            float* __restrict__ out, const int* __restrict__ perm,
            const float* __restrict__ wrow,
            const int* __restrict__ tbl_e, const int* __restrict__ tbl_r0,
            const int* __restrict__ nblk) {
  __shared__ u16 S[49152];
  const int bx = blockIdx.x, by = blockIdx.y;
  const int tid = threadIdx.x;
  const int w = tid >> 6, lane = tid & 63;
  const int lm = lane & 15, lq = lane >> 4;
  const int wm = w >> 2, wn = w & 3;
  const int srow = w * 8 + (lane >> 3);
  const int c8 = lane & 7;

  const bool routed = bx >= 32;
  int r0, K, ld;
  const u16 *Ab, *Bb;
  if (!routed) {
    r0 = bx * BM;
    Ab = hbS; K = DIMD; ld = DIMD;
    Bb = sw2ct;
  } else {
    const int rbx = bx - 32;
    if (rbx >= *nblk) return;
    const int e = tbl_e[rbx];
    r0 = tbl_r0[rbx];
    Ab = hbR; K = HIDD; ld = HIDD;
    Bb = w2t + (size_t)e * (size_t)DIMD * HIDD;
  }
  const int n0 = by * BN;
  const u16* gA0 = Ab + (size_t)(r0 + srow) * ld + (c8 ^ ((srow >> 1) & 7)) * 8;
  const u16* gA1 = Ab + (size_t)(r0 + 64 + srow) * ld + (c8 ^ (((64 + srow) >> 1) & 7)) * 8;
  const u16* gB[4];
#pragma unroll
  for (int p = 0; p < 4; ++p) {
    const int n = p * 64 + srow;
    gB[p] = Bb + (size_t)(n0 + n) * ld + (c8 ^ ((n >> 1) & 7)) * 8;
  }
  int aoff[4][2], boff[4][2];
#pragma unroll
  for (int i = 0; i < 4; ++i) {
    const int m = wm * 64 + i * 16 + lm;
    const int n = wn * 64 + i * 16 + lm;
#pragma unroll
    for (int kh = 0; kh < 2; ++kh) {
      aoff[i][kh] = m * 64 + (((kh << 2) | lq) ^ ((m >> 1) & 7)) * 8;
      boff[i][kh] = n * 64 + (((kh << 2) | lq) ^ ((n >> 1) & 7)) * 8;
    }
  }
  f32x4 acc[4][4];
#pragma unroll
  for (int i = 0; i < 4; ++i)
#pragma unroll
    for (int j = 0; j < 4; ++j) {
      acc[i][j][0] = 0.f; acc[i][j][1] = 0.f; acc[i][j][2] = 0.f; acc[i][j][3] = 0.f;
    }

  gemm_pipe(gA0, gA1, gB[0], gB[1], gB[2], gB[3], K, S, aoff, boff, acc, w);

#pragma unroll
  for (int i = 0; i < 4; ++i) {
#pragma unroll
    for (int r = 0; r < 4; ++r) {
      const int rr = r0 + wm * 64 + i * 16 + lq * 4 + r;
      int t; float wt;
      if (!routed) { t = rr; wt = 1.f; }
      else { t = perm[rr]; wt = (t >= 0) ? wrow[rr] : 0.f; }
      if (t >= 0) {
        float* dst = &out[(size_t)t * DIMD];
#pragma unroll
        for (int j = 0; j < 4; ++j) {
          const int gc = n0 + wn * 64 + j * 16 + lm;
          atomicAdd(&dst[gc], wt * acc[i][j][r]);
        }
      }
    }
  }
}

// ---------------- launch ----------------

extern "C" void kernel_launch(void* const* d_in, const int* in_sizes, int n_in,
                              void* d_out, int out_size, void* d_ws, size_t ws_size,
                              hipStream_t stream) {
  const float* x   = (const float*)d_in[0];
  const float* gw  = (const float*)d_in[1];
  const float* sw1 = (const float*)d_in[2];
  const float* sw2 = (const float*)d_in[3];
  const float* w1  = (const float*)d_in[4];
  const float* w2  = (const float*)d_in[5];
  float* out = (float*)d_out;

  char* ws = (char*)d_ws;
  u16* xb    = (u16*)(ws);                         // 16 MB
  u16* hbS   = (u16*)(ws + (size_t)( 16 << 20));   // 16 MB  [4096][2048]
  u16* hbR   = (u16*)(ws + (size_t)( 32 << 20));   // 20 MB  [10240][1024]
  u16* sw1t  = (u16*)(ws + (size_t)( 56 << 20));   //  8 MB  [2][1024][2048] (concat n)
  u16* sw2ct = (u16*)(ws + (size_t)( 64 << 20));   //  8 MB  [2048][2*1024] concat k
  u16* w1t   = (u16*)(ws + (size_t)( 72 << 20));   // 64 MB  [16][1024][2048]
  u16* w2t   = (u16*)(ws + (size_t)(136 << 20));   // 64 MB  [16][2048][1024]
  char* p = ws + (size_t)(200 << 20);
  int*   top2i   = (int*)p;    p += T_TOK * 2 * 4;
  float* top2w   = (float*)p;  p += T_TOK * 2 * 4;
  int*   perm    = (int*)p;    p += RMAX * 4;
  float* wrow    = (float*)p;  p += RMAX * 4;
  int*   cnt     = (int*)p;    p += 16 * 4;
  int*   fill    = (int*)p;    p += 16 * 4;
  int*   offs    = (int*)p;    p += 32 * 4;
  int*   tbl_e   = (int*)p;    p += MAXBLK * 4;
  int*   tbl_r0  = (int*)p;    p += MAXBLK * 4;
  int*   nblk    = (int*)p;    p += 16 * 4;
  float* partial = (float*)p;  p += 256 * 16 * 4;

  // fused zero(out) + cvt(x) + init
  k_pre<<<(T_TOK * DIMD / 4) / 256, 256, 0, stream>>>(x, xb, out, perm, cnt, fill);
  k_gate<<<T_TOK / 16, 256, 0, stream>>>(x, gw, top2i, top2w, cnt, partial);
  k_off<<<1, 64, 0, stream>>>(cnt, offs, tbl_e, tbl_r0, nblk);
  k_fill<<<(T_TOK * 2 + 255) / 256, 256, 0, stream>>>(top2i, top2w, offs, fill, perm, wrow);
  k_aux<<<1, 256, 0, stream>>>(partial, out + (size_t)T_TOK * DIMD);

  // weight transposes (fp32 [K][N] -> bf16 [n][k]) — distinct symbols
  k_tr2<0><<<dim3(16, 32,  2), 256, 0, stream>>>(sw1, sw1t, 2048, 1024, 1024l * 2048, 2048);
  k_tr2<1><<<dim3(32, 16,  2), 256, 0, stream>>>(sw2, sw2ct, 1024, 2048, 1024, 2048);
  k_tr2<2><<<dim3(16, 32, 16), 256, 0, stream>>>(w1, w1t, 2048, 1024, 1024l * 2048, 2048);
  k_tr2<3><<<dim3(32, 16, 16), 256, 0, stream>>>(w2, w2t, 1024, 2048, 2048l * 1024, 1024);

  // fused up-projection: shared 32 row-blocks x 8 n-tiles (concat N=2048) +
  // routed <=96 row-blocks x 4 n-tiles (N=1024)
  k_up<<<dim3(32 + MAXBLK, 8), 512, 0, stream>>>(xb, sw1t, w1t, hbS, hbR,
                                                 perm, tbl_e, tbl_r0, nblk);
  // fused down-projection: shared 32 + routed <=96 row-blocks, 8 n-tiles
  k_down<<<dim3(32 + MAXBLK, 8), 512, 0, stream>>>(hbS, hbR, sw2ct, w2t, out,
                                                   perm, wrow, tbl_e, tbl_r0, nblk);
}

// Round 6
// 762.692 us; speedup vs baseline: 1.1173x; 1.0574x over previous
//
#include <hip/hip_runtime.h>
#include <math.h>

typedef unsigned short u16;
typedef __bf16 bf16x8 __attribute__((ext_vector_type(8)));
typedef float f32x4 __attribute__((ext_vector_type(4)));
typedef unsigned short u16x8 __attribute__((ext_vector_type(8)));

#define T_TOK 4096
#define DIMD 2048
#define HIDD 1024
#define NEXP 16
#define RMAX 10240
#define MAXBLK 96
#define BM 128
#define BN 256
#define BK 64

__device__ __forceinline__ u16 f2b(float f) {
  unsigned u = __builtin_bit_cast(unsigned, f);
  unsigned r = (u + 0x7FFFu + ((u >> 16) & 1u)) >> 16;  // RNE
  return (u16)r;
}

__device__ __forceinline__ void gld16(const void* g, void* l) {
  __builtin_amdgcn_global_load_lds(
      (const __attribute__((address_space(1))) void*)g,
      (__attribute__((address_space(3))) void*)l, 16, 0, 0);
}

// ---------------- small kernels ----------------

// fused: cvt(x->xb bf16) + init(perm/cnt). out is NOT zeroed (k_down shared
// stores cover it; k_post accumulates routed on top).
__global__ void k_pre(const float* __restrict__ x, u16* __restrict__ xb,
                      int* __restrict__ perm, int* __restrict__ cnt) {
  const int i = blockIdx.x * blockDim.x + threadIdx.x;  // 0 .. T*D/4-1
  const float4 v = ((const float4*)x)[i];
  union { u16 u[4]; unsigned long long q; } t;
  t.u[0] = f2b(v.x); t.u[1] = f2b(v.y); t.u[2] = f2b(v.z); t.u[3] = f2b(v.w);
  ((unsigned long long*)xb)[i] = t.q;
  if (i < RMAX) perm[i] = -1;
  if (i < NEXP) cnt[i] = 0;
}

// gating: fp32 logits = x @ gate_w, softmax, top-2, partial prob sums
__global__ __launch_bounds__(256)
void k_gate(const float* __restrict__ x, const float* __restrict__ gw,
            int* __restrict__ top2i, float* __restrict__ top2w,
            int* __restrict__ cnt, float* __restrict__ partial) {
  const int e = threadIdx.x & 15;
  const int tt = threadIdx.x >> 4;
  const int t = blockIdx.x * 16 + tt;
  const float* xp = x + (size_t)t * DIMD;
  float acc = 0.f;
#pragma unroll 8
  for (int k = 0; k < DIMD; ++k) acc = fmaf(xp[k], gw[k * NEXP + e], acc);
  __shared__ float lg[16][17];
  __shared__ float pr[16][17];
  lg[tt][e] = acc;
  __syncthreads();
  if (e == 0) {
    float l[16];
    float mx = -1e30f;
    for (int j = 0; j < 16; ++j) { l[j] = lg[tt][j]; mx = fmaxf(mx, l[j]); }
    float s = 0.f;
    for (int j = 0; j < 16; ++j) { l[j] = expf(l[j] - mx); s += l[j]; }
    const float inv = 1.f / s;
    float p1 = -1.f, p2 = -1.f; int i1 = 0, i2 = 0;
    for (int j = 0; j < 16; ++j) {
      const float p = l[j] * inv;
      pr[tt][j] = p;
      if (p > p1) { p2 = p1; i2 = i1; p1 = p; i1 = j; }
      else if (p > p2) { p2 = p; i2 = j; }
    }
    const float wsum = p1 + p2;
    top2i[t * 2 + 0] = i1;
    top2i[t * 2 + 1] = i2;
    top2w[t * 2 + 0] = p1 / wsum;
    top2w[t * 2 + 1] = p2 / wsum;
    atomicAdd(&cnt[i1], 1);
    atomicAdd(&cnt[i2], 1);
  }
  __syncthreads();
  if (tt == 0) {
    float s = 0.f;
    for (int j = 0; j < 16; ++j) s += pr[j][e];
    partial[blockIdx.x * 16 + e] = s;
  }
}

// merged scheduler: offsets+block-table (lane0), fill (LDS counters), aux.
__global__ __launch_bounds__(256)
void k_sched(const int* __restrict__ cnt, const int* __restrict__ top2i,
             const float* __restrict__ top2w, const float* __restrict__ partial,
             int* __restrict__ tbl_e, int* __restrict__ tbl_r0,
             int* __restrict__ nblk, int* __restrict__ perm,
             float* __restrict__ wrow, int* __restrict__ slot2,
             float* __restrict__ auxOut) {
  __shared__ int offs[17];
  __shared__ int lfill[16];
  __shared__ float s[16][17];
  const int tid = threadIdx.x;
  if (tid == 0) {
    int o = 0, nb = 0;
    for (int e = 0; e < NEXP; ++e) {
      offs[e] = o;
      const int b = (cnt[e] + BM - 1) / BM;
      for (int i = 0; i < b; ++i) { tbl_e[nb] = e; tbl_r0[nb] = o + i * BM; ++nb; }
      o += b * BM;
    }
    offs[16] = o;
    nblk[0] = nb;
  }
  if (tid < 16) lfill[tid] = 0;
  __syncthreads();
  for (int id = tid; id < T_TOK * 2; id += 256) {
    const int e = top2i[id];
    const int pos = atomicAdd(&lfill[e], 1);
    const int r = offs[e] + pos;
    perm[r] = id >> 1;
    wrow[r] = top2w[id];
    slot2[id] = r;
  }
  // aux loss reduction
  const int e = tid & 15, c = tid >> 4;
  float a = 0.f;
  for (int b = c; b < 256; b += 16) a += partial[b * 16 + e];
  s[c][e] = a;
  __syncthreads();
  if (tid == 0) {
    float aux = 0.f;
    for (int j = 0; j < 16; ++j) {
      float tot = 0.f;
      for (int cc = 0; cc < 16; ++cc) tot += s[cc][j];
      const float m = tot / (float)T_TOK;
      aux += m * m;
    }
    auxOut[0] = aux * (float)NEXP;
  }
}

// merged weight transpose+convert: one dispatch for all 4 tensors.
// z 0..15: w1[e] [2048][1024] -> w1t[e] [1024][2048]
// z 16..31: w2[e] [1024][2048] -> w2t[e] [2048][1024]
// z 32..33: sw1[s] -> sw1t (concat-n rows s*1024..)
// z 34..35: sw2[s] -> sw2ct (concat-k cols s*1024..)
__global__ __launch_bounds__(256)
void k_trW(const float* __restrict__ w1, const float* __restrict__ w2,
           const float* __restrict__ sw1, const float* __restrict__ sw2,
           u16* __restrict__ w1t, u16* __restrict__ w2t,
           u16* __restrict__ sw1t, u16* __restrict__ sw2ct) {
  const int z = blockIdx.z;
  const float* W; u16* Wo; int K, N, ldo;
  if (z < 16) {
    W = w1 + (size_t)z * 2048 * 1024;
    Wo = w1t + (size_t)z * 1024 * 2048;
    K = 2048; N = 1024; ldo = 2048;
  } else if (z < 32) {
    W = w2 + (size_t)(z - 16) * 1024 * 2048;
    Wo = w2t + (size_t)(z - 16) * 2048 * 1024;
    K = 1024; N = 2048; ldo = 1024;
  } else if (z < 34) {
    W = sw1 + (size_t)(z - 32) * 2048 * 1024;
    Wo = sw1t + (size_t)(z - 32) * 1024 * 2048;
    K = 2048; N = 1024; ldo = 2048;
  } else {
    W = sw2 + (size_t)(z - 34) * 1024 * 2048;
    Wo = sw2ct + (size_t)(z - 34) * 1024;
    K = 1024; N = 2048; ldo = 2048;
  }
  const int n0 = blockIdx.x * 64, k0 = blockIdx.y * 64;
  if (n0 >= N || k0 >= K) return;
  __shared__ float t[64][65];
  {
    const int r = threadIdx.x >> 4;
    const int c = (threadIdx.x & 15) * 4;
#pragma unroll
    for (int p = 0; p < 4; ++p) {
      const int kk = p * 16 + r;
      const float4 v = *(const float4*)&W[(size_t)(k0 + kk) * N + n0 + c];
      t[kk][c] = v.x; t[kk][c + 1] = v.y; t[kk][c + 2] = v.z; t[kk][c + 3] = v.w;
    }
  }
  __syncthreads();
  {
    const int r2 = threadIdx.x >> 3;        // 0..31 n-row
    const int g8 = (threadIdx.x & 7) * 8;   // k-group
#pragma unroll
    for (int p = 0; p < 2; ++p) {
      const int nn = p * 32 + r2;
      u16x8 o;
#pragma unroll
      for (int i = 0; i < 8; ++i) o[i] = f2b(t[g8 + i][nn]);
      *(u16x8*)&Wo[(size_t)(n0 + nn) * ldo + k0 + g8] = o;
    }
  }
}

// epilogue gather: out[t] += w0*rbuf[s0] + w1*rbuf[s1]
__global__ __launch_bounds__(512)
void k_post(float* __restrict__ out, const float* __restrict__ rbLo,
            const float* __restrict__ rbHi, const int* __restrict__ slot2,
            const float* __restrict__ wrow) {
  const int t = blockIdx.x;
  const int d4 = threadIdx.x;  // 512 x float4 = 2048
  const int s0 = slot2[t * 2], s1 = slot2[t * 2 + 1];
  const float w0 = wrow[s0], w1 = wrow[s1];
  const float4* r0 = (const float4*)(s0 < 8192 ? rbLo + (size_t)s0 * DIMD
                                               : rbHi + (size_t)(s0 - 8192) * DIMD);
  const float4* r1 = (const float4*)(s1 < 8192 ? rbLo + (size_t)s1 * DIMD
                                               : rbHi + (size_t)(s1 - 8192) * DIMD);
  float4* op = (float4*)(out + (size_t)t * DIMD);
  float4 o = op[d4];
  const float4 a = r0[d4], b = r1[d4];
  o.x += w0 * a.x + w1 * b.x;
  o.y += w0 * a.y + w1 * b.y;
  o.z += w0 * a.z + w1 * b.z;
  o.w += w0 * a.w + w1 * b.w;
  op[d4] = o;
}

// ---------------- GEMM core: counted-vmcnt ring-2 pipeline (R3/R5) --------
// Tile BM=128 x BN=256, BK=64. 512 threads = 8 waves (2M x 4N), 64x64 C/wave.
// LDS per buffer: A 16KB + B 32KB; ring of 2 = 96KB.
// Swizzle (conflicts measured 0): LDS slot (row, chunk c) holds global chunk
// c ^ ((row>>1)&7); applied on per-lane GLOBAL source + ds_read address.
// Per K-tile: compute(buf) ; bar ; stage(t+2 -> buf) ; vmcnt(6) ; bar.

__device__ __forceinline__ void stage_tile(
    const u16* gA0, const u16* gA1, const u16* gB0, const u16* gB1,
    const u16* gB2, const u16* gB3, int k0, u16* S, int b, int w) {
  u16* As = S + b * 24576;
  u16* Bs = As + 8192;
  gld16(gA0 + k0, As + w * 512);
  gld16(gA1 + k0, As + 4096 + w * 512);
  gld16(gB0 + k0, Bs + w * 512);
  gld16(gB1 + k0, Bs + 4096 + w * 512);
  gld16(gB2 + k0, Bs + 8192 + w * 512);
  gld16(gB3 + k0, Bs + 12288 + w * 512);
}

__device__ __forceinline__ void comp_tile(const u16* __restrict__ S, int b,
    const int (&aoff)[4][2], const int (&boff)[4][2], f32x4 (&acc)[4][4]) {
  const u16* As = S + b * 24576;
  const u16* Bs = As + 8192;
#pragma unroll
  for (int kh = 0; kh < 2; ++kh) {
    bf16x8 a[4], bq[4];
#pragma unroll
    for (int i = 0; i < 4; ++i) a[i] = *(const bf16x8*)(As + aoff[i][kh]);
#pragma unroll
    for (int j = 0; j < 4; ++j) bq[j] = *(const bf16x8*)(Bs + boff[j][kh]);
    __builtin_amdgcn_s_setprio(1);
#pragma unroll
    for (int i = 0; i < 4; ++i)
#pragma unroll
      for (int j = 0; j < 4; ++j)
        acc[i][j] = __builtin_amdgcn_mfma_f32_16x16x32_bf16(a[i], bq[j], acc[i][j], 0, 0, 0);
    __builtin_amdgcn_s_setprio(0);
  }
}

#define FENCE asm volatile("" ::: "memory")
#define VMW6  asm volatile("s_waitcnt vmcnt(6)" ::: "memory")
#define VMW0  asm volatile("s_waitcnt vmcnt(0)" ::: "memory")

__device__ __forceinline__ void gemm_pipe(
    const u16* gA0, const u16* gA1, const u16* gB0, const u16* gB1,
    const u16* gB2, const u16* gB3, int K, u16* S,
    const int (&aoff)[4][2], const int (&boff)[4][2],
    f32x4 (&acc)[4][4], int w) {
  const int nt = K >> 6;  // even (16 or 32)
  stage_tile(gA0, gA1, gB0, gB1, gB2, gB3, 0, S, 0, w);
  stage_tile(gA0, gA1, gB0, gB1, gB2, gB3, 64, S, 1, w);
  VMW6;                              // tile0 landed (tile1's 6 in flight)
  __builtin_amdgcn_s_barrier();
  FENCE;
  for (int t = 0; t < nt - 2; ++t) {
    comp_tile(S, t & 1, aoff, boff, acc);
    FENCE;
    __builtin_amdgcn_s_barrier();    // all waves done reading buf (t&1)
    FENCE;
    stage_tile(gA0, gA1, gB0, gB1, gB2, gB3, (t + 2) << 6, S, t & 1, w);
    VMW6;                            // tile t+1 landed; t+2's 6 in flight
    __builtin_amdgcn_s_barrier();
    FENCE;
  }
  comp_tile(S, 0, aoff, boff, acc);  // tile nt-2
  VMW0;                              // tile nt-1 landed
  __builtin_amdgcn_s_barrier();
  FENCE;
  comp_tile(S, 1, aoff, boff, acc);  // tile nt-1
}

// Fused up-projection. Shared (bx<32): concat-N B = sw1t [2048n][2048k],
// out hbS [4096][2048]. Routed (bx>=32, by<4): per-expert B, out hbR.
__global__ __launch_bounds__(512, 2)
void k_up(const u16* __restrict__ xb, const u16* __restrict__ sw1t,
          const u16* __restrict__ w1t, u16* __restrict__ hbS,
          u16* __restrict__ hbR, const int* __restrict__ perm,
          const int* __restrict__ tbl_e, const int* __restrict__ tbl_r0,
          const int* __restrict__ nblk) {
  __shared__ u16 S[49152];  // 96 KB
  const int bx = blockIdx.x, by = blockIdx.y;
  const int tid = threadIdx.x;
  const int w = tid >> 6, lane = tid & 63;
  const int lm = lane & 15, lq = lane >> 4;
  const int wm = w >> 2, wn = w & 3;
  const int srow = w * 8 + (lane >> 3);  // 0..63 staging row
  const int c8 = lane & 7;               // 16B chunk within 64-elem row

  const bool routed = bx >= 32;
  int r0, ga0, ga1;
  const u16* Bb;
  if (!routed) {
    r0 = bx * BM;
    Bb = sw1t;  // concat-n [2048][2048]
    ga0 = r0 + srow; ga1 = r0 + 64 + srow;
  } else {
    if (by >= 4) return;
    const int rbx = bx - 32;
    if (rbx >= *nblk) return;
    const int e = tbl_e[rbx];
    r0 = tbl_r0[rbx];
    Bb = w1t + (size_t)e * (size_t)HIDD * DIMD;
    const int p0 = perm[r0 + srow];      ga0 = (p0 < 0) ? 0 : p0;
    const int p1 = perm[r0 + 64 + srow]; ga1 = (p1 < 0) ? 0 : p1;
  }
  const int n0 = by * BN;
  // pre-swizzled global sources (linear LDS dest => swizzle on source)
  const u16* gA0 = xb + (size_t)ga0 * DIMD + (c8 ^ ((srow >> 1) & 7)) * 8;
  const u16* gA1 = xb + (size_t)ga1 * DIMD + (c8 ^ (((64 + srow) >> 1) & 7)) * 8;
  const u16* gB[4];
#pragma unroll
  for (int p = 0; p < 4; ++p) {
    const int n = p * 64 + srow;
    gB[p] = Bb + (size_t)(n0 + n) * DIMD + (c8 ^ ((n >> 1) & 7)) * 8;
  }
  int aoff[4][2], boff[4][2];
#pragma unroll
  for (int i = 0; i < 4; ++i) {
    const int m = wm * 64 + i * 16 + lm;
    const int n = wn * 64 + i * 16 + lm;
#pragma unroll
    for (int kh = 0; kh < 2; ++kh) {
      aoff[i][kh] = m * 64 + (((kh << 2) | lq) ^ ((m >> 1) & 7)) * 8;
      boff[i][kh] = n * 64 + (((kh << 2) | lq) ^ ((n >> 1) & 7)) * 8;
    }
  }
  f32x4 acc[4][4];
#pragma unroll
  for (int i = 0; i < 4; ++i)
#pragma unroll
    for (int j = 0; j < 4; ++j) {
      acc[i][j][0] = 0.f; acc[i][j][1] = 0.f; acc[i][j][2] = 0.f; acc[i][j][3] = 0.f;
    }

  gemm_pipe(gA0, gA1, gB[0], gB[1], gB[2], gB[3], DIMD, S, aoff, boff, acc, w);

#pragma unroll
  for (int i = 0; i < 4; ++i) {
#pragma unroll
    for (int r = 0; r < 4; ++r) {
      const int row = r0 + wm * 64 + i * 16 + lq * 4 + r;
      u16* dst = routed ? &hbR[(size_t)row * HIDD] : &hbS[(size_t)row * DIMD];
#pragma unroll
      for (int j = 0; j < 4; ++j) {
        const int gc = n0 + wn * 64 + j * 16 + lm;
        const float v = acc[i][j][r];
        const float s = v / (1.f + expf(-v));
        dst[gc] = f2b(s);
      }
    }
  }
}

// Fused down-projection: shared (bx<32, A=hbS K=2048) + routed (bx>=32,
// A=hbR K=1024). N=2048 (by<8). NO atomics: shared -> plain fp32 store to out
// (covers every element exactly once); routed -> plain fp32 store of the
// UNWEIGHTED result into rbuf (overlaid on w1t[64MB]+xb[16MB], both dead).
__global__ __launch_bounds__(512, 2)
void k_down(const u16* __restrict__ hbS, const u16* __restrict__ hbR,
            const u16* __restrict__ sw2ct, const u16* __restrict__ w2t,
            float* __restrict__ out, float* __restrict__ rbLo,
            float* __restrict__ rbHi, const int* __restrict__ tbl_e,
            const int* __restrict__ tbl_r0, const int* __restrict__ nblk) {
  __shared__ u16 S[49152];
  const int bx = blockIdx.x, by = blockIdx.y;
  const int tid = threadIdx.x;
  const int w = tid >> 6, lane = tid & 63;
  const int lm = lane & 15, lq = lane >> 4;
  const int wm = w >> 2, wn = w & 3;
  const int srow = w * 8 + (lane >> 3);
  const int c8 = lane & 7;

  const bool routed = bx >= 32;
  int r0, K, ld;
  const u16 *Ab, *Bb;
  if (!routed) {
    r0 = bx * BM;
    Ab = hbS; K = DIMD; ld = DIMD;
    Bb = sw2ct;
  } else {
    const int rbx = bx - 32;
    if (rbx >= *nblk) return;
    const int e = tbl_e[rbx];
    r0 = tbl_r0[rbx];
    Ab = hbR; K = HIDD; ld = HIDD;
    Bb = w2t + (size_t)e * (size_t)DIMD * HIDD;
  }
  const int n0 = by * BN;
  const u16* gA0 = Ab + (size_t)(r0 + srow) * ld + (c8 ^ ((srow >> 1) & 7)) * 8;
  const u16* gA1 = Ab + (size_t)(r0 + 64 + srow) * ld + (c8 ^ (((64 + srow) >> 1) & 7)) * 8;
  const u16* gB[4];
#pragma unroll
  for (int p = 0; p < 4; ++p) {
    const int n = p * 64 + srow;
    gB[p] = Bb + (size_t)(n0 + n) * ld + (c8 ^ ((n >> 1) & 7)) * 8;
  }
  int aoff[4][2], boff[4][2];
#pragma unroll
  for (int i = 0; i < 4; ++i) {
    const int m = wm * 64 + i * 16 + lm;
    const int n = wn * 64 + i * 16 + lm;
#pragma unroll
    for (int kh = 0; kh < 2; ++kh) {
      aoff[i][kh] = m * 64 + (((kh << 2) | lq) ^ ((m >> 1) & 7)) * 8;
      boff[i][kh] = n * 64 + (((kh << 2) | lq) ^ ((n >> 1) & 7)) * 8;
    }
  }
  f32x4 acc[4][4];
#pragma unroll
  for (int i = 0; i < 4; ++i)
#pragma unroll
    for (int j = 0; j < 4; ++j) {
      acc[i][j][0] = 0.f; acc[i][j][1] = 0.f; acc[i][j][2] = 0.f; acc[i][j][3] = 0.f;
    }

  gemm_pipe(gA0, gA1, gB[0], gB[1], gB[2], gB[3], K, S, aoff, boff, acc, w);

#pragma unroll
  for (int i = 0; i < 4; ++i) {
#pragma unroll
    for (int r = 0; r < 4; ++r) {
      const int rr = r0 + wm * 64 + i * 16 + lq * 4 + r;
      float* dst;
      if (!routed) dst = out + (size_t)rr * DIMD;
      else dst = (rr < 8192) ? rbLo + (size_t)rr * DIMD
                             : rbHi + (size_t)(rr - 8192) * DIMD;
#pragma unroll
      for (int j = 0; j < 4; ++j) {
        const int gc = n0 + wn * 64 + j * 16 + lm;
        dst[gc] = acc[i][j][r];
      }
    }
  }
}

// ---------------- launch ----------------

extern "C" void kernel_launch(void* const* d_in, const int* in_sizes, int n_in,
                              void* d_out, int out_size, void* d_ws, size_t ws_size,
                              hipStream_t stream) {
  const float* x   = (const float*)d_in[0];
  const float* gw  = (const float*)d_in[1];
  const float* sw1 = (const float*)d_in[2];
  const float* sw2 = (const float*)d_in[3];
  const float* w1  = (const float*)d_in[4];
  const float* w2  = (const float*)d_in[5];
  float* out = (float*)d_out;

  char* ws = (char*)d_ws;
  u16* xb    = (u16*)(ws);                         // 16 MB (reused as rbHi)
  u16* hbS   = (u16*)(ws + (size_t)( 16 << 20));   // 16 MB  [4096][2048]
  u16* hbR   = (u16*)(ws + (size_t)( 32 << 20));   // 20 MB  [10240][1024]
  u16* sw1t  = (u16*)(ws + (size_t)( 56 << 20));   //  8 MB  [2][1024][2048] concat-n
  u16* sw2ct = (u16*)(ws + (size_t)( 64 << 20));   //  8 MB  [2048][2*1024] concat-k
  u16* w1t   = (u16*)(ws + (size_t)( 72 << 20));   // 64 MB  (reused as rbLo)
  u16* w2t   = (u16*)(ws + (size_t)(136 << 20));   // 64 MB  [16][2048][1024]
  // routed-down staging overlays buffers dead after k_up:
  float* rbLo = (float*)(ws + (size_t)( 72 << 20)); // rows 0..8191    (= w1t)
  float* rbHi = (float*)(ws);                       // rows 8192..10239 (= xb)
  char* p = ws + (size_t)(200 << 20);
  int*   top2i   = (int*)p;    p += T_TOK * 2 * 4;
  float* top2w   = (float*)p;  p += T_TOK * 2 * 4;
  int*   perm    = (int*)p;    p += RMAX * 4;
  float* wrow    = (float*)p;  p += RMAX * 4;
  int*   slot2   = (int*)p;    p += T_TOK * 2 * 4;
  int*   cnt     = (int*)p;    p += 16 * 4;
  int*   tbl_e   = (int*)p;    p += MAXBLK * 4;
  int*   tbl_r0  = (int*)p;    p += MAXBLK * 4;
  int*   nblk    = (int*)p;    p += 16 * 4;
  float* partial = (float*)p;  p += 256 * 16 * 4;

  // cvt + init
  k_pre<<<(T_TOK * DIMD / 4) / 256, 256, 0, stream>>>(x, xb, perm, cnt);
  // gating
  k_gate<<<T_TOK / 16, 256, 0, stream>>>(x, gw, top2i, top2w, cnt, partial);
  // offsets + fill + aux (single block)
  k_sched<<<1, 256, 0, stream>>>(cnt, top2i, top2w, partial, tbl_e, tbl_r0,
                                 nblk, perm, wrow, slot2,
                                 out + (size_t)T_TOK * DIMD);
  // all weight transposes in ONE dispatch (named, profilable)
  k_trW<<<dim3(32, 32, 36), 256, 0, stream>>>(w1, w2, sw1, sw2,
                                              w1t, w2t, sw1t, sw2ct);
  // fused up-projection
  k_up<<<dim3(32 + MAXBLK, 8), 512, 0, stream>>>(xb, sw1t, w1t, hbS, hbR,
                                                 perm, tbl_e, tbl_r0, nblk);
  // fused down-projection (no atomics; routed -> rbuf staging)
  k_down<<<dim3(32 + MAXBLK, 8), 512, 0, stream>>>(hbS, hbR, sw2ct, w2t, out,
                                                   rbLo, rbHi, tbl_e, tbl_r0, nblk);
  // weighted gather of routed contributions
  k_post<<<T_TOK, 512, 0, stream>>>(out, rbLo, rbHi, slot2, wrow);
}

// Round 7
// 746.928 us; speedup vs baseline: 1.1409x; 1.0211x over previous
//
#include <hip/hip_runtime.h>
#include <math.h>

typedef unsigned short u16;
typedef __bf16 bf16x8 __attribute__((ext_vector_type(8)));
typedef float f32x4 __attribute__((ext_vector_type(4)));
typedef unsigned short u16x8 __attribute__((ext_vector_type(8)));

#define T_TOK 4096
#define DIMD 2048
#define HIDD 1024
#define NEXP 16
#define RMAX 12288
#define MAXBLK 48
#define BM 256
#define BN 256

__device__ __forceinline__ u16 f2b(float f) {
  unsigned u = __builtin_bit_cast(unsigned, f);
  unsigned r = (u + 0x7FFFu + ((u >> 16) & 1u)) >> 16;  // RNE
  return (u16)r;
}

__device__ __forceinline__ void gld16(const void* g, void* l) {
  __builtin_amdgcn_global_load_lds(
      (const __attribute__((address_space(1))) void*)g,
      (__attribute__((address_space(3))) void*)l, 16, 0, 0);
}

// ---------------- small kernels ----------------

// fused: cvt(x->xb bf16) + init(perm/perm2/cnt)
__global__ void k_pre(const float* __restrict__ x, u16* __restrict__ xb,
                      int* __restrict__ perm, int* __restrict__ perm2,
                      int* __restrict__ cnt) {
  const int i = blockIdx.x * blockDim.x + threadIdx.x;
  const float4 v = ((const float4*)x)[i];
  union { u16 u[4]; unsigned long long q; } t;
  t.u[0] = f2b(v.x); t.u[1] = f2b(v.y); t.u[2] = f2b(v.z); t.u[3] = f2b(v.w);
  ((unsigned long long*)xb)[i] = t.q;
  if (i < RMAX) { perm[i] = -1; perm2[i] = -1; }
  if (i < NEXP) cnt[i] = 0;
}

// gating: fp32 logits = x @ gate_w, softmax, top-2, partial prob sums
__global__ __launch_bounds__(256)
void k_gate(const float* __restrict__ x, const float* __restrict__ gw,
            int* __restrict__ top2i, float* __restrict__ top2w,
            int* __restrict__ cnt, float* __restrict__ partial) {
  const int e = threadIdx.x & 15;
  const int tt = threadIdx.x >> 4;
  const int t = blockIdx.x * 16 + tt;
  const float* xp = x + (size_t)t * DIMD;
  float acc = 0.f;
#pragma unroll 8
  for (int k = 0; k < DIMD; ++k) acc = fmaf(xp[k], gw[k * NEXP + e], acc);
  __shared__ float lg[16][17];
  __shared__ float pr[16][17];
  lg[tt][e] = acc;
  __syncthreads();
  if (e == 0) {
    float l[16];
    float mx = -1e30f;
    for (int j = 0; j < 16; ++j) { l[j] = lg[tt][j]; mx = fmaxf(mx, l[j]); }
    float s = 0.f;
    for (int j = 0; j < 16; ++j) { l[j] = expf(l[j] - mx); s += l[j]; }
    const float inv = 1.f / s;
    float p1 = -1.f, p2 = -1.f; int i1 = 0, i2 = 0;
    for (int j = 0; j < 16; ++j) {
      const float p = l[j] * inv;
      pr[tt][j] = p;
      if (p > p1) { p2 = p1; i2 = i1; p1 = p; i1 = j; }
      else if (p > p2) { p2 = p; i2 = j; }
    }
    const float wsum = p1 + p2;
    top2i[t * 2 + 0] = i1;
    top2i[t * 2 + 1] = i2;
    top2w[t * 2 + 0] = p1 / wsum;
    top2w[t * 2 + 1] = p2 / wsum;
    atomicAdd(&cnt[i1], 1);
    atomicAdd(&cnt[i2], 1);
  }
  __syncthreads();
  if (tt == 0) {
    float s = 0.f;
    for (int j = 0; j < 16; ++j) s += pr[j][e];
    partial[blockIdx.x * 16 + e] = s;
  }
}

// merged scheduler: offsets+block-table (lane0), fill (LDS counters), aux.
__global__ __launch_bounds__(256)
void k_sched(const int* __restrict__ cnt, const int* __restrict__ top2i,
             const float* __restrict__ top2w, const float* __restrict__ partial,
             int* __restrict__ tbl_e, int* __restrict__ tbl_r0,
             int* __restrict__ nblk, int* __restrict__ perm,
             int* __restrict__ perm2, float* __restrict__ auxOut) {
  __shared__ int offs[17];
  __shared__ int lfill[16];
  __shared__ float s[16][17];
  const int tid = threadIdx.x;
  if (tid == 0) {
    int o = 0, nb = 0;
    for (int e = 0; e < NEXP; ++e) {
      offs[e] = o;
      const int b = (cnt[e] + BM - 1) / BM;
      for (int i = 0; i < b; ++i) { tbl_e[nb] = e; tbl_r0[nb] = o + i * BM; ++nb; }
      o += b * BM;
    }
    offs[16] = o;
    nblk[0] = nb;
  }
  if (tid < 16) lfill[tid] = 0;
  __syncthreads();
  for (int id = tid; id < T_TOK * 2; id += 256) {
    const int e = top2i[id];
    const int pos = atomicAdd(&lfill[e], 1);
    const int r = offs[e] + pos;
    perm[r] = id >> 1;   // token (A gather in k_up)
    perm2[r] = id;       // slot id (routed-down staging row)
  }
  const int e = tid & 15, c = tid >> 4;
  float a = 0.f;
  for (int b = c; b < 256; b += 16) a += partial[b * 16 + e];
  s[c][e] = a;
  __syncthreads();
  if (tid == 0) {
    float aux = 0.f;
    for (int j = 0; j < 16; ++j) {
      float tot = 0.f;
      for (int cc = 0; cc < 16; ++cc) tot += s[cc][j];
      const float m = tot / (float)T_TOK;
      aux += m * m;
    }
    auxOut[0] = aux * (float)NEXP;
  }
}

// merged weight transpose+convert (fp32 [K][N] -> bf16 [n][k]) for all 4 tensors
__global__ __launch_bounds__(256)
void k_trW(const float* __restrict__ w1, const float* __restrict__ w2,
           const float* __restrict__ sw1, const float* __restrict__ sw2,
           u16* __restrict__ w1t, u16* __restrict__ w2t,
           u16* __restrict__ sw1t, u16* __restrict__ sw2ct) {
  const int z = blockIdx.z;
  const float* W; u16* Wo; int K, N, ldo;
  if (z < 16) {
    W = w1 + (size_t)z * 2048 * 1024;  Wo = w1t + (size_t)z * 1024 * 2048;
    K = 2048; N = 1024; ldo = 2048;
  } else if (z < 32) {
    W = w2 + (size_t)(z - 16) * 1024 * 2048;  Wo = w2t + (size_t)(z - 16) * 2048 * 1024;
    K = 1024; N = 2048; ldo = 1024;
  } else if (z < 34) {
    W = sw1 + (size_t)(z - 32) * 2048 * 1024;  Wo = sw1t + (size_t)(z - 32) * 1024 * 2048;
    K = 2048; N = 1024; ldo = 2048;
  } else {
    W = sw2 + (size_t)(z - 34) * 1024 * 2048;  Wo = sw2ct + (size_t)(z - 34) * 1024;
    K = 1024; N = 2048; ldo = 2048;
  }
  const int n0 = blockIdx.x * 64, k0 = blockIdx.y * 64;
  if (n0 >= N || k0 >= K) return;
  __shared__ float t[64][65];
  {
    const int r = threadIdx.x >> 4;
    const int c = (threadIdx.x & 15) * 4;
#pragma unroll
    for (int p = 0; p < 4; ++p) {
      const int kk = p * 16 + r;
      const float4 v = *(const float4*)&W[(size_t)(k0 + kk) * N + n0 + c];
      t[kk][c] = v.x; t[kk][c + 1] = v.y; t[kk][c + 2] = v.z; t[kk][c + 3] = v.w;
    }
  }
  __syncthreads();
  {
    const int r2 = threadIdx.x >> 3;
    const int g8 = (threadIdx.x & 7) * 8;
#pragma unroll
    for (int p = 0; p < 2; ++p) {
      const int nn = p * 32 + r2;
      u16x8 o;
#pragma unroll
      for (int i = 0; i < 8; ++i) o[i] = f2b(t[g8 + i][nn]);
      *(u16x8*)&Wo[(size_t)(n0 + nn) * ldo + k0 + g8] = o;
    }
  }
}

// epilogue gather: out[t] += w(2t)*rb[2t] + w(2t+1)*rb[2t+1]
__global__ __launch_bounds__(512)
void k_post(float* __restrict__ out, const float* __restrict__ rb,
            const float* __restrict__ top2w) {
  const int t = blockIdx.x;
  const int d4 = threadIdx.x;
  const float w0 = top2w[t * 2], w1 = top2w[t * 2 + 1];
  const float4 a = ((const float4*)(rb + (size_t)(2 * t) * DIMD))[d4];
  const float4 b = ((const float4*)(rb + (size_t)(2 * t + 1) * DIMD))[d4];
  float4* op = (float4*)(out + (size_t)t * DIMD);
  float4 o = op[d4];
  o.x += w0 * a.x + w1 * b.x;
  o.y += w0 * a.y + w1 * b.y;
  o.z += w0 * a.z + w1 * b.z;
  o.w += w0 * a.w + w1 * b.w;
  op[d4] = o;
}

// ---------------- GEMM: m201-style 8-phase 256x256 schedule ----------------
// 512 threads = 8 waves (2M x 4N); per-wave C = 128x64 = acc[8][4].
// LDS 128KB: 2 dbuf x {A0,A1,B0,B1} halves (each 128 rows x 64 k bf16 = 16KB).
// u16 offsets: buf d at d*32768; A-half h at h*8192; B-half g at 16384+g*8192;
// line l (64 rows) at l*4096; wave slot w*512.
// Swizzle (T2): LDS (half-local row rr, chunk c) holds global chunk
// c ^ ((rr>>1)&7); applied on per-lane GLOBAL source (linear LDS dest) and on
// ds_read addresses. Measured 0 bank conflicts with this scheme (R3).
// Per iteration (2 K-tiles t0->buf0, t1->buf1), 8 phases; each phase:
//   {ds_read A-quadrant [+B at ph1/5]} ; {stage one half-tile (2 gloads)} ;
//   barrier ; 16 MFMA (setprio) ; barrier.   vmcnt(6) at phases 4 & 8 only.
// Stage stream: ph1:A.l1(t1)->buf1 | ph2:B0(t2) ph3:B1(t2) ph4:A.l0(t2)
// ph5:A.l1(t2)->buf0 | ph6:B0(t3) ph7:B1(t3) ph8:A.l0(t3)->buf1.
// Hand-checked: every overwrite is >=1 barrier after last read; every first
// use is >=7 loads behind a vmcnt(6) checkpoint. Last iteration: skip t2/t3
// stages, vmcnt(0) at phase 4.

#define FENCE asm volatile("" ::: "memory")
#define VMW6  asm volatile("s_waitcnt vmcnt(6)" ::: "memory")
#define VMW0  asm volatile("s_waitcnt vmcnt(0)" ::: "memory")
#define BARR  do { FENCE; __builtin_amdgcn_s_barrier(); FENCE; } while (0)

struct GP { const u16* a[2][2]; const u16* b[2][2]; };  // [half][line]

__device__ __forceinline__ void stA(const GP& g, u16* S, int w512, int D, int L, int K) {
  gld16(g.a[0][L] + K, S + D + L * 4096 + w512);
  gld16(g.a[1][L] + K, S + D + 8192 + L * 4096 + w512);
}
__device__ __forceinline__ void stB(const GP& g, u16* S, int w512, int D, int G, int K) {
  gld16(g.b[G][0] + K, S + D + 16384 + G * 8192 + w512);
  gld16(g.b[G][1] + K, S + D + 16384 + G * 8192 + 4096 + w512);
}
__device__ __forceinline__ void rdA(const u16* S, int D, const int (&aoff)[8][2],
                                    int q, bf16x8 (&af)[4]) {
  af[0] = *(const bf16x8*)(S + D + aoff[2 * q][0]);
  af[1] = *(const bf16x8*)(S + D + aoff[2 * q][1]);
  af[2] = *(const bf16x8*)(S + D + aoff[2 * q + 1][0]);
  af[3] = *(const bf16x8*)(S + D + aoff[2 * q + 1][1]);
}
__device__ __forceinline__ void rdB(const u16* S, int D, const int (&boff)[4][2],
                                    bf16x8 (&bf)[4][2]) {
#pragma unroll
  for (int nf = 0; nf < 4; ++nf) {
    bf[nf][0] = *(const bf16x8*)(S + D + boff[nf][0]);
    bf[nf][1] = *(const bf16x8*)(S + D + boff[nf][1]);
  }
}
__device__ __forceinline__ void mm16(f32x4 (&acc)[8][4], const bf16x8 (&af)[4],
                                     const bf16x8 (&bf)[4][2], int q) {
  __builtin_amdgcn_s_setprio(1);
#pragma unroll
  for (int kh = 0; kh < 2; ++kh)
#pragma unroll
    for (int mi = 0; mi < 2; ++mi)
#pragma unroll
      for (int nf = 0; nf < 4; ++nf)
        acc[2 * q + mi][nf] = __builtin_amdgcn_mfma_f32_16x16x32_bf16(
            af[mi * 2 + kh], bf[nf][kh], acc[2 * q + mi][nf], 0, 0, 0);
  __builtin_amdgcn_s_setprio(0);
}

template <bool LAST>
__device__ __forceinline__ void iter8(u16* S, int w512, const GP& g,
    int k1, int k2, int k3, const int (&aoff)[8][2], const int (&boff)[4][2],
    f32x4 (&acc)[8][4]) {
  bf16x8 af[4], bf[4][2];
  // P1  (tile t0 from buf0, quadrant 0; B-frags for whole tile)
  rdA(S, 0, aoff, 0, af); rdB(S, 0, boff, bf);
  stA(g, S, w512, 32768, 1, k1);           // finish buf1's A (tile t1)
  BARR; mm16(acc, af, bf, 0); BARR;
  // P2
  rdA(S, 0, aoff, 1, af);
  if (!LAST) stB(g, S, w512, 0, 0, k2);
  BARR; mm16(acc, af, bf, 1); BARR;
  // P3
  rdA(S, 0, aoff, 2, af);
  if (!LAST) stB(g, S, w512, 0, 1, k2);
  BARR; mm16(acc, af, bf, 2); BARR;
  // P4
  rdA(S, 0, aoff, 3, af);
  if (!LAST) stA(g, S, w512, 0, 0, k2);
  if (LAST) { VMW0; } else { VMW6; }
  BARR; mm16(acc, af, bf, 3); BARR;
  // P5  (tile t1 from buf1)
  rdA(S, 32768, aoff, 0, af); rdB(S, 32768, boff, bf);
  if (!LAST) stA(g, S, w512, 0, 1, k2);
  BARR; mm16(acc, af, bf, 0); BARR;
  // P6
  rdA(S, 32768, aoff, 1, af);
  if (!LAST) stB(g, S, w512, 32768, 0, k3);
  BARR; mm16(acc, af, bf, 1); BARR;
  // P7
  rdA(S, 32768, aoff, 2, af);
  if (!LAST) stB(g, S, w512, 32768, 1, k3);
  BARR; mm16(acc, af, bf, 2); BARR;
  // P8
  rdA(S, 32768, aoff, 3, af);
  if (!LAST) { stA(g, S, w512, 32768, 0, k3); VMW6; }
  BARR; mm16(acc, af, bf, 3); BARR;
}

__device__ __forceinline__ void gemm8(u16* S, int w512, const GP& g, int K,
    const int (&aoff)[8][2], const int (&boff)[4][2], f32x4 (&acc)[8][4]) {
  // prologue: t0 fully (8 loads), then t1's B + A.l0 (6 loads)
  stB(g, S, w512, 0, 0, 0);  stB(g, S, w512, 0, 1, 0);
  stA(g, S, w512, 0, 0, 0);  stA(g, S, w512, 0, 1, 0);
  stB(g, S, w512, 32768, 0, 64);  stB(g, S, w512, 32768, 1, 64);
  stA(g, S, w512, 32768, 0, 64);
  VMW6;                                  // t0 landed; t1's 6 may be in flight
  BARR;
  const int nIt = K >> 7;                // 2 K-tiles (128 k) per iteration
  for (int j = 0; j < nIt - 1; ++j)
    iter8<false>(S, w512, g, (2 * j + 1) * 64, (2 * j + 2) * 64,
                 (2 * j + 3) * 64, aoff, boff, acc);
  iter8<true>(S, w512, g, K - 64, 0, 0, aoff, boff, acc);
}

// Fused up-projection. Shared (bx<16): B=sw1t concat-n [2048][2048], out hbS.
// Routed (bx>=16, by<4): per-expert B=w1t[e], out hbR. K=2048, ld=2048 all.
__global__ __launch_bounds__(512, 2)
void k_up(const u16* __restrict__ xb, const u16* __restrict__ sw1t,
          const u16* __restrict__ w1t, u16* __restrict__ hbS,
          u16* __restrict__ hbR, const int* __restrict__ perm,
          const int* __restrict__ tbl_e, const int* __restrict__ tbl_r0,
          const int* __restrict__ nblk) {
  __shared__ u16 S[65536];  // 128 KB
  const int bx = blockIdx.x, by = blockIdx.y;
  const int tid = threadIdx.x;
  const int w = tid >> 6, lane = tid & 63;
  const int lm = lane & 15, lq = lane >> 4;
  const int wm = w >> 2, wn = w & 3;
  const int srow = w * 8 + (lane >> 3);
  const int c8 = lane & 7;
  const int w512 = w * 512;

  const bool routed = bx >= 16;
  int r0; const u16* Bb;
  if (!routed) {
    r0 = bx * BM;
    Bb = sw1t;
  } else {
    if (by >= 4) return;
    const int rbx = bx - 16;
    if (rbx >= *nblk) return;
    const int e = tbl_e[rbx];
    r0 = tbl_r0[rbx];
    Bb = w1t + (size_t)e * (size_t)HIDD * DIMD;
  }
  const int n0 = by * BN;

  GP g;
#pragma unroll
  for (int l = 0; l < 2; ++l) {
    const int co = (c8 ^ (((l * 64 + srow) >> 1) & 7)) * 8;
#pragma unroll
    for (int h = 0; h < 2; ++h) {
      const int tr = r0 + h * 128 + l * 64 + srow;
      int ga;
      if (!routed) ga = tr;
      else { const int p = perm[tr]; ga = (p < 0) ? 0 : p; }
      g.a[h][l] = xb + (size_t)ga * DIMD + co;
    }
#pragma unroll
    for (int gg = 0; gg < 2; ++gg)
      g.b[gg][l] = Bb + (size_t)(n0 + gg * 128 + l * 64 + srow) * DIMD + co;
  }
  int aoff[8][2], boff[4][2];
#pragma unroll
  for (int mi = 0; mi < 8; ++mi) {
    const int m = mi * 16 + lm;
#pragma unroll
    for (int kh = 0; kh < 2; ++kh) {
      const int kc = kh * 4 + lq;
      aoff[mi][kh] = wm * 8192 + m * 64 + ((kc ^ ((m >> 1) & 7)) * 8);
    }
  }
#pragma unroll
  for (int nf = 0; nf < 4; ++nf) {
    const int nlh = (wn & 1) * 64 + nf * 16 + lm;
#pragma unroll
    for (int kh = 0; kh < 2; ++kh) {
      const int kc = kh * 4 + lq;
      boff[nf][kh] = 16384 + (wn >> 1) * 8192 + nlh * 64 + ((kc ^ ((nlh >> 1) & 7)) * 8);
    }
  }
  f32x4 acc[8][4];
#pragma unroll
  for (int i = 0; i < 8; ++i)
#pragma unroll
    for (int j = 0; j < 4; ++j) {
      acc[i][j][0] = 0.f; acc[i][j][1] = 0.f; acc[i][j][2] = 0.f; acc[i][j][3] = 0.f;
    }

  gemm8(S, w512, g, DIMD, aoff, boff, acc);

#pragma unroll
  for (int mi = 0; mi < 8; ++mi) {
#pragma unroll
    for (int r = 0; r < 4; ++r) {
      const int row = r0 + wm * 128 + mi * 16 + lq * 4 + r;
      u16* dst = routed ? hbR + (size_t)row * HIDD : hbS + (size_t)row * DIMD;
#pragma unroll
      for (int nf = 0; nf < 4; ++nf) {
        const int gc = n0 + wn * 64 + nf * 16 + lm;
        const float v = acc[mi][nf][r];
        const float s = v / (1.f + expf(-v));
        dst[gc] = f2b(s);
      }
    }
  }
}

// Fused down-projection. Shared (bx<16): A=hbS K=2048 ld=2048, B=sw2ct,
// plain fp32 store to out. Routed (bx>=16): A=hbR K=1024 ld=1024, B=w2t[e],
// unweighted fp32 store by slot-id into rb (overlaid on dead w1t).
__global__ __launch_bounds__(512, 2)
void k_down(const u16* __restrict__ hbS, const u16* __restrict__ hbR,
            const u16* __restrict__ sw2ct, const u16* __restrict__ w2t,
            float* __restrict__ out, float* __restrict__ rb,
            const int* __restrict__ perm2, const int* __restrict__ tbl_e,
            const int* __restrict__ tbl_r0, const int* __restrict__ nblk) {
  __shared__ u16 S[65536];
  const int bx = blockIdx.x, by = blockIdx.y;
  const int tid = threadIdx.x;
  const int w = tid >> 6, lane = tid & 63;
  const int lm = lane & 15, lq = lane >> 4;
  const int wm = w >> 2, wn = w & 3;
  const int srow = w * 8 + (lane >> 3);
  const int c8 = lane & 7;
  const int w512 = w * 512;

  const bool routed = bx >= 16;
  int r0, K, ld;
  const u16 *Ab, *Bb;
  if (!routed) {
    r0 = bx * BM;
    Ab = hbS; K = DIMD; ld = DIMD;
    Bb = sw2ct;
  } else {
    const int rbx = bx - 16;
    if (rbx >= *nblk) return;
    const int e = tbl_e[rbx];
    r0 = tbl_r0[rbx];
    Ab = hbR; K = HIDD; ld = HIDD;
    Bb = w2t + (size_t)e * (size_t)DIMD * HIDD;
  }
  const int n0 = by * BN;

  GP g;
#pragma unroll
  for (int l = 0; l < 2; ++l) {
    const int co = (c8 ^ (((l * 64 + srow) >> 1) & 7)) * 8;
#pragma unroll
    for (int h = 0; h < 2; ++h)
      g.a[h][l] = Ab + (size_t)(r0 + h * 128 + l * 64 + srow) * ld + co;
#pragma unroll
    for (int gg = 0; gg < 2; ++gg)
      g.b[gg][l] = Bb + (size_t)(n0 + gg * 128 + l * 64 + srow) * ld + co;
  }
  int aoff[8][2], boff[4][2];
#pragma unroll
  for (int mi = 0; mi < 8; ++mi) {
    const int m = mi * 16 + lm;
#pragma unroll
    for (int kh = 0; kh < 2; ++kh) {
      const int kc = kh * 4 + lq;
      aoff[mi][kh] = wm * 8192 + m * 64 + ((kc ^ ((m >> 1) & 7)) * 8);
    }
  }
#pragma unroll
  for (int nf = 0; nf < 4; ++nf) {
    const int nlh = (wn & 1) * 64 + nf * 16 + lm;
#pragma unroll
    for (int kh = 0; kh < 2; ++kh) {
      const int kc = kh * 4 + lq;
      boff[nf][kh] = 16384 + (wn >> 1) * 8192 + nlh * 64 + ((kc ^ ((nlh >> 1) & 7)) * 8);
    }
  }
  f32x4 acc[8][4];
#pragma unroll
  for (int i = 0; i < 8; ++i)
#pragma unroll
    for (int j = 0; j < 4; ++j) {
      acc[i][j][0] = 0.f; acc[i][j][1] = 0.f; acc[i][j][2] = 0.f; acc[i][j][3] = 0.f;
    }

  gemm8(S, w512, g, K, aoff, boff, acc);

#pragma unroll
  for (int mi = 0; mi < 8; ++mi) {
#pragma unroll
    for (int r = 0; r < 4; ++r) {
      const int row = r0 + wm * 128 + mi * 16 + lq * 4 + r;
      if (!routed) {
        float* dst = out + (size_t)row * DIMD;
#pragma unroll
        for (int nf = 0; nf < 4; ++nf)
          dst[n0 + wn * 64 + nf * 16 + lm] = acc[mi][nf][r];
      } else {
        const int id2 = perm2[row];
        if (id2 >= 0) {
          float* dst = rb + (size_t)id2 * DIMD;
#pragma unroll
          for (int nf = 0; nf < 4; ++nf)
            dst[n0 + wn * 64 + nf * 16 + lm] = acc[mi][nf][r];
        }
      }
    }
  }
}

// ---------------- launch ----------------

extern "C" void kernel_launch(void* const* d_in, const int* in_sizes, int n_in,
                              void* d_out, int out_size, void* d_ws, size_t ws_size,
                              hipStream_t stream) {
  const float* x   = (const float*)d_in[0];
  const float* gw  = (const float*)d_in[1];
  const float* sw1 = (const float*)d_in[2];
  const float* sw2 = (const float*)d_in[3];
  const float* w1  = (const float*)d_in[4];
  const float* w2  = (const float*)d_in[5];
  float* out = (float*)d_out;

  char* ws = (char*)d_ws;
  u16* xb    = (u16*)(ws);                         // 16 MB
  u16* hbS   = (u16*)(ws + (size_t)( 16 << 20));   // 16 MB  [4096][2048]
  u16* hbR   = (u16*)(ws + (size_t)( 32 << 20));   // 24 MB  [12288][1024]
  u16* sw1t  = (u16*)(ws + (size_t)( 56 << 20));   //  8 MB  [2048 n][2048 k] concat-n
  u16* sw2ct = (u16*)(ws + (size_t)( 64 << 20));   //  8 MB  [2048 n][2*1024 k] concat-k
  u16* w1t   = (u16*)(ws + (size_t)( 72 << 20));   // 64 MB  (reused as rb after k_up)
  u16* w2t   = (u16*)(ws + (size_t)(136 << 20));   // 64 MB  [16][2048][1024]
  float* rb  = (float*)(ws + (size_t)( 72 << 20)); // 64 MB  [8192 slots][2048] fp32
  char* p = ws + (size_t)(200 << 20);
  int*   top2i   = (int*)p;    p += T_TOK * 2 * 4;
  float* top2w   = (float*)p;  p += T_TOK * 2 * 4;
  int*   perm    = (int*)p;    p += RMAX * 4;
  int*   perm2   = (int*)p;    p += RMAX * 4;
  int*   cnt     = (int*)p;    p += 16 * 4;
  int*   tbl_e   = (int*)p;    p += MAXBLK * 4;
  int*   tbl_r0  = (int*)p;    p += MAXBLK * 4;
  int*   nblk    = (int*)p;    p += 16 * 4;
  float* partial = (float*)p;  p += 256 * 16 * 4;

  k_pre<<<(T_TOK * DIMD / 4) / 256, 256, 0, stream>>>(x, xb, perm, perm2, cnt);
  k_gate<<<T_TOK / 16, 256, 0, stream>>>(x, gw, top2i, top2w, cnt, partial);
  k_sched<<<1, 256, 0, stream>>>(cnt, top2i, top2w, partial, tbl_e, tbl_r0,
                                 nblk, perm, perm2, out + (size_t)T_TOK * DIMD);
  k_trW<<<dim3(32, 32, 36), 256, 0, stream>>>(w1, w2, sw1, sw2,
                                              w1t, w2t, sw1t, sw2ct);
  // up: shared 16 row-blocks x 8 n-tiles + routed <=48 x 4 n-tiles
  k_up<<<dim3(16 + MAXBLK, 8), 512, 0, stream>>>(xb, sw1t, w1t, hbS, hbR,
                                                 perm, tbl_e, tbl_r0, nblk);
  // down: shared 16 x 8 + routed <=48 x 8 (N=2048 both)
  k_down<<<dim3(16 + MAXBLK, 8), 512, 0, stream>>>(hbS, hbR, sw2ct, w2t, out,
                                                   rb, perm2, tbl_e, tbl_r0, nblk);
  // weighted routed gather
  k_post<<<T_TOK, 512, 0, stream>>>(out, rb, top2w);
}